// Round 1
// baseline (1723.933 us; speedup 1.0000x reference)
//
#include <hip/hip_runtime.h>
#include <hip/hip_bf16.h>
#include <math.h>

// Problem constants (from reference)
#define N_NODES 4096
#define DIN     256
#define E       512
#define NH      8
#define HD      64
#define NEDGE   131072

// Epilogue modes for the generic GEMM
enum { EPI_NONE = 0, EPI_BIAS = 1, EPI_CE = 2, EPI_SCALE = 3, EPI_MASKSCALE = 4 };

// C[M,N] = A[M,K] @ op(B) (+ epilogue)
//   BT=true : B is [N,K] row-major (C = A @ B^T)
//   BT=false: B is [K,N] row-major (C = A @ B)
// grid: (N/64, M/64, ksplits). ksplits>1 requires ATOMIC=true and pre-zeroed C.
// All M,N,K used here are multiples of 64/64/16 respectively — no bounds checks.
template<bool BT, int EPI, bool ATOMIC>
__global__ __launch_bounds__(256)
void gemm_k(const float* __restrict__ A, int lda,
            const float* __restrict__ B, int ldb,
            float* __restrict__ C, int ldc, int K,
            const float* __restrict__ bias,
            const float* __restrict__ cemb, const int* __restrict__ ctype,
            const unsigned* __restrict__ mask, float scale)
{
    __shared__ float As[16][68];   // k-major, padded: float4 reads stay 16B-aligned
    __shared__ float Bs[16][68];

    const int t  = threadIdx.x;
    const int m0 = blockIdx.y * 64;
    const int n0 = blockIdx.x * 64;
    const int kchunk = K / (int)gridDim.z;
    const int k0 = blockIdx.z * kchunk;
    const int k1 = k0 + kchunk;
    const int ty = t >> 4, tx = t & 15;

    float acc[4][4] = {{0.f}};

    for (int kt = k0; kt < k1; kt += 16) {
        {   // stage A tile (transpose to k-major)
            const int row = t >> 2, kq = (t & 3) << 2;
            const float4 va = *(const float4*)(A + (size_t)(m0 + row) * lda + kt + kq);
            As[kq + 0][row] = va.x; As[kq + 1][row] = va.y;
            As[kq + 2][row] = va.z; As[kq + 3][row] = va.w;
        }
        if (BT) {
            const int row = t >> 2, kq = (t & 3) << 2;
            const float4 vb = *(const float4*)(B + (size_t)(n0 + row) * ldb + kt + kq);
            Bs[kq + 0][row] = vb.x; Bs[kq + 1][row] = vb.y;
            Bs[kq + 2][row] = vb.z; Bs[kq + 3][row] = vb.w;
        } else {
            const int kk = t >> 4, nq = (t & 15) << 2;
            *(float4*)&Bs[kk][nq] = *(const float4*)(B + (size_t)(kt + kk) * ldb + n0 + nq);
        }
        __syncthreads();
        #pragma unroll
        for (int k = 0; k < 16; ++k) {
            const float4 av = *(const float4*)&As[k][ty << 2];
            const float4 bv = *(const float4*)&Bs[k][tx << 2];
            const float a[4] = {av.x, av.y, av.z, av.w};
            const float b[4] = {bv.x, bv.y, bv.z, bv.w};
            #pragma unroll
            for (int i = 0; i < 4; ++i)
                #pragma unroll
                for (int j = 0; j < 4; ++j)
                    acc[i][j] = fmaf(a[i], b[j], acc[i][j]);
        }
        __syncthreads();
    }

    #pragma unroll
    for (int i = 0; i < 4; ++i) {
        const int row = m0 + (ty << 2) + i;
        const int col = n0 + (tx << 2);
        float r[4];
        #pragma unroll
        for (int j = 0; j < 4; ++j) r[j] = acc[i][j];

        if (EPI == EPI_BIAS) {
            #pragma unroll
            for (int j = 0; j < 4; ++j) r[j] += bias[col + j];
        } else if (EPI == EPI_CE) {
            const int c = ctype[row];
            #pragma unroll
            for (int j = 0; j < 4; ++j) r[j] += 0.1f * cemb[(size_t)c * E + col + j];
        } else if (EPI == EPI_SCALE) {
            #pragma unroll
            for (int j = 0; j < 4; ++j) r[j] *= scale;
        } else if (EPI == EPI_MASKSCALE) {
            // col is 4-aligned and (col&31)<=28 so all 4 bits live in one word
            const unsigned w = mask[(size_t)row * (N_NODES / 32) + (col >> 5)];
            #pragma unroll
            for (int j = 0; j < 4; ++j)
                r[j] = ((w >> ((col & 31) + j)) & 1u) ? r[j] * scale : -1e9f;
        }

        if (ATOMIC) {
            #pragma unroll
            for (int j = 0; j < 4; ++j)
                atomicAdd(&C[(size_t)row * ldc + col + j], r[j]);
        } else {
            float4 rv; rv.x = r[0]; rv.y = r[1]; rv.z = r[2]; rv.w = r[3];
            *(float4*)&C[(size_t)row * ldc + col] = rv;
        }
    }
}

__device__ inline float waveMax(float v) {
    #pragma unroll
    for (int o = 32; o; o >>= 1) v = fmaxf(v, __shfl_xor(v, o));
    return v;
}
__device__ inline float waveSum(float v) {
    #pragma unroll
    for (int o = 32; o; o >>= 1) v += __shfl_xor(v, o);
    return v;
}

// Row softmax over a 4096-wide row, in place. Row held in registers (64 f32/thread).
// ENT: also accumulate -sum(p*log(p+1e-10)) into *ent_acc.
template<bool ENT>
__global__ __launch_bounds__(256)
void softmax_row_k(float* __restrict__ buf, float* __restrict__ ent_acc)
{
    const int row = blockIdx.x;
    float* p = buf + (size_t)row * N_NODES;
    const int t = threadIdx.x;
    const int w = t >> 6;
    __shared__ float red[4];

    float4 v[4];
    #pragma unroll
    for (int s = 0; s < 4; ++s) v[s] = *(const float4*)(p + s * 1024 + t * 4);

    float m = -3.4e38f;
    #pragma unroll
    for (int s = 0; s < 4; ++s)
        m = fmaxf(m, fmaxf(fmaxf(v[s].x, v[s].y), fmaxf(v[s].z, v[s].w)));
    m = waveMax(m);
    if ((t & 63) == 0) red[w] = m;
    __syncthreads();
    m = fmaxf(fmaxf(red[0], red[1]), fmaxf(red[2], red[3]));

    float sum = 0.f;
    #pragma unroll
    for (int s = 0; s < 4; ++s) {
        v[s].x = expf(v[s].x - m); v[s].y = expf(v[s].y - m);
        v[s].z = expf(v[s].z - m); v[s].w = expf(v[s].w - m);
        sum += v[s].x + v[s].y + v[s].z + v[s].w;
    }
    sum = waveSum(sum);
    __syncthreads();
    if ((t & 63) == 0) red[w] = sum;
    __syncthreads();
    sum = red[0] + red[1] + red[2] + red[3];
    const float inv = 1.0f / sum;

    float ent = 0.f;
    #pragma unroll
    for (int s = 0; s < 4; ++s) {
        v[s].x *= inv; v[s].y *= inv; v[s].z *= inv; v[s].w *= inv;
        if (ENT) {
            ent -= v[s].x * logf(v[s].x + 1e-10f);
            ent -= v[s].y * logf(v[s].y + 1e-10f);
            ent -= v[s].z * logf(v[s].z + 1e-10f);
            ent -= v[s].w * logf(v[s].w + 1e-10f);
        }
        *(float4*)(p + s * 1024 + t * 4) = v[s];
    }
    if (ENT) {
        ent = waveSum(ent);
        __syncthreads();
        if ((t & 63) == 0) red[w] = ent;
        __syncthreads();
        if (t == 0) atomicAdd(ent_acc, red[0] + red[1] + red[2] + red[3]);
    }
}

__global__ __launch_bounds__(256)
void mask_build_k(const int* __restrict__ ei, unsigned* __restrict__ mask)
{
    const int i = blockIdx.x * 256 + threadIdx.x;   // NEDGE threads
    const int r = ei[i];
    const int c = ei[NEDGE + i];
    atomicOr(&mask[(size_t)r * (N_NODES / 32) + (c >> 5)], 1u << (c & 31));
}

__global__ __launch_bounds__(256)
void phase_k(const float* __restrict__ Q, const float* __restrict__ K,
             float* __restrict__ out)
{
    const size_t i = (size_t)blockIdx.x * 256 + threadIdx.x;
    out[i] = atan2f(K[i], Q[i]);    // angle of complex(Q, K): arctan2(K, Q)
}

__global__ void coh_k(const float* __restrict__ ent, float* __restrict__ out)
{
    out[0] = 1.0f - ent[0] / logf(4096.0f);
}

extern "C" void kernel_launch(void* const* d_in, const int* in_sizes, int n_in,
                              void* d_out, int out_size, void* d_ws, size_t ws_size,
                              hipStream_t stream)
{
    const float* x    = (const float*)d_in[0];
    const int*   ei   = (const int*)  d_in[1];
    const int*   ct   = (const int*)  d_in[2];
    const float* Wq   = (const float*)d_in[3];
    const float* bq   = (const float*)d_in[4];
    const float* Wk   = (const float*)d_in[5];
    const float* bk   = (const float*)d_in[6];
    const float* Wv   = (const float*)d_in[7];
    const float* bv   = (const float*)d_in[8];
    const float* bio  = (const float*)d_in[9];
    const float* cemb = (const float*)d_in[10];
    const float* ipw  = (const float*)d_in[11];
    const float* ipb  = (const float*)d_in[12];
    const float* ow   = (const float*)d_in[13];
    const float* ob   = (const float*)d_in[14];

    const size_t NE = (size_t)N_NODES * E;          // 2,097,152 floats
    float* bufA = (float*)d_ws;                     // Q0 -> q
    float* bufB = bufA + NE;                        // K0 -> k
    float* bufC = bufB + NE;                        // V  -> o (MHA out)
    float* bufD = bufC + NE;                        // Q (post-bio)
    float* bufE = bufD + NE;                        // K (post-bio)
    unsigned* mask = (unsigned*)(bufE + NE);        // 4096 x 128 words = 2 MB
    float* entAcc  = (float*)(mask + (size_t)N_NODES * (N_NODES / 32));

    float* outAttended = (float*)d_out;                       // [4096,512]
    float* outAttn  = outAttended + NE;                       // [4096,4096]
    float* outPhase = outAttn + (size_t)N_NODES * N_NODES;    // [4096,512]
    float* outCoh   = outPhase + NE;                          // scalar
    float* vScratch = outPhase;   // phase region doubles as v-scratch until phase is written

    const dim3 blk(256);
    const dim3 gProj(E / 64, N_NODES / 64, 1);       // (8, 64)
    const dim3 gScore(N_NODES / 64, N_NODES / 64, 1);// (64, 64)

    // 1. Q0/K0/V projections: X @ W^T + b
    gemm_k<true, EPI_BIAS, false><<<gProj, blk, 0, stream>>>(x, DIN, Wq, DIN, bufA, E, DIN, bq, nullptr, nullptr, nullptr, 0.f);
    gemm_k<true, EPI_BIAS, false><<<gProj, blk, 0, stream>>>(x, DIN, Wk, DIN, bufB, E, DIN, bk, nullptr, nullptr, nullptr, 0.f);
    gemm_k<true, EPI_BIAS, false><<<gProj, blk, 0, stream>>>(x, DIN, Wv, DIN, bufC, E, DIN, bv, nullptr, nullptr, nullptr, 0.f);

    // 2. bio mixing + 0.1*cell_emb:  Q = Q0 @ bio + ce,  K = K0 @ bio^T + ce
    gemm_k<false, EPI_CE, false><<<gProj, blk, 0, stream>>>(bufA, E, bio, E, bufD, E, E, nullptr, cemb, ct, nullptr, 0.f);
    gemm_k<true,  EPI_CE, false><<<gProj, blk, 0, stream>>>(bufB, E, bio, E, bufE, E, E, nullptr, cemb, ct, nullptr, 0.f);

    // 3. in_proj: q = Q@wq_i^T+b, k = K@wk_i^T+b, v = V@wv_i^T+b
    gemm_k<true, EPI_BIAS, false><<<gProj, blk, 0, stream>>>(bufD, E, ipw,             E, bufA,     E, E, ipb,         nullptr, nullptr, nullptr, 0.f);
    gemm_k<true, EPI_BIAS, false><<<gProj, blk, 0, stream>>>(bufE, E, ipw + (size_t)E*E,   E, bufB,     E, E, ipb + E,     nullptr, nullptr, nullptr, 0.f);
    gemm_k<true, EPI_BIAS, false><<<gProj, blk, 0, stream>>>(bufC, E, ipw + (size_t)2*E*E, E, vScratch, E, E, ipb + 2 * E, nullptr, nullptr, nullptr, 0.f);

    // 4. 8-head dense attention (scores materialized in the attn output region)
    hipMemsetAsync(bufC, 0, NE * sizeof(float), stream);   // o accumulator
    for (int h = 0; h < NH; ++h) {
        gemm_k<true, EPI_SCALE, false><<<gScore, blk, 0, stream>>>(
            bufA + h * HD, E, bufB + h * HD, E, outAttn, N_NODES, HD,
            nullptr, nullptr, nullptr, nullptr, 0.125f);               // 1/sqrt(64)
        softmax_row_k<false><<<N_NODES, blk, 0, stream>>>(outAttn, nullptr);
        gemm_k<false, EPI_NONE, true><<<dim3(1, 64, 16), blk, 0, stream>>>(
            outAttn, N_NODES, vScratch + h * HD, E, bufC + h * HD, E, N_NODES,
            nullptr, nullptr, nullptr, nullptr, 0.f);                  // split-K atomic PV
    }

    // 5. attended = o @ out_w^T + out_b
    gemm_k<true, EPI_BIAS, false><<<gProj, blk, 0, stream>>>(bufC, E, ow, E, outAttended, E, E, ob, nullptr, nullptr, nullptr, 0.f);

    // 6. phase = atan2(K, Q)  (frees the v-scratch region by overwriting it)
    phase_k<<<dim3((unsigned)(NE / 256)), blk, 0, stream>>>(bufD, bufE, outPhase);

    // 7. edge mask + entropy accumulator
    hipMemsetAsync(mask, 0, (size_t)N_NODES * (N_NODES / 32) * sizeof(unsigned), stream);
    hipMemsetAsync(entAcc, 0, sizeof(float), stream);
    mask_build_k<<<dim3(NEDGE / 256), blk, 0, stream>>>(ei, mask);

    // 8. masked scores = (Q @ K^T) * (1/sqrt(512)) with mask -> -1e9
    gemm_k<true, EPI_MASKSCALE, false><<<gScore, blk, 0, stream>>>(
        bufD, E, bufE, E, outAttn, N_NODES, E,
        nullptr, nullptr, nullptr, mask, (float)(1.0 / sqrt(512.0)));

    // 9. softmax rows + entropy
    softmax_row_k<true><<<N_NODES, blk, 0, stream>>>(outAttn, entAcc);

    // 10. coherence
    coh_k<<<1, 1, 0, stream>>>(entAcc, outCoh);
}

// Round 2
// 621.975 us; speedup vs baseline: 2.7717x; 2.7717x over previous
//
#include <hip/hip_runtime.h>
#include <hip/hip_bf16.h>
#include <math.h>

#define N_NODES 4096
#define DIN     256
#define E       512
#define NH      8
#define HD      64
#define NEDGE   131072
#define MAXE    1024   // max edges/row; Poisson(32) tail at 1024 is ~0

typedef short bf16x8 __attribute__((ext_vector_type(8)));
typedef float f32x4  __attribute__((ext_vector_type(4)));

__device__ inline short f2bf(float f) {
    __hip_bfloat16 h = __float2bfloat16(f);   // RNE
    return __builtin_bit_cast(short, h);
}

// ---------------- generic fp32 tiled GEMM (kept for Q/K-precision chain) ----
enum { EPI_BIAS = 1, EPI_CE = 2 };

template<bool BT, int EPI>
__global__ __launch_bounds__(256)
void gemm_k(const float* __restrict__ A, int lda,
            const float* __restrict__ B, int ldb,
            float* __restrict__ C, int ldc, int K,
            const float* __restrict__ bias,
            const float* __restrict__ cemb, const int* __restrict__ ctype)
{
    __shared__ float As[16][68];
    __shared__ float Bs[16][68];

    const int t  = threadIdx.x;
    const int m0 = blockIdx.y * 64;
    const int n0 = blockIdx.x * 64;
    const int ty = t >> 4, tx = t & 15;

    float acc[4][4] = {{0.f}};

    for (int kt = 0; kt < K; kt += 16) {
        {
            const int row = t >> 2, kq = (t & 3) << 2;
            const float4 va = *(const float4*)(A + (size_t)(m0 + row) * lda + kt + kq);
            As[kq + 0][row] = va.x; As[kq + 1][row] = va.y;
            As[kq + 2][row] = va.z; As[kq + 3][row] = va.w;
        }
        if (BT) {
            const int row = t >> 2, kq = (t & 3) << 2;
            const float4 vb = *(const float4*)(B + (size_t)(n0 + row) * ldb + kt + kq);
            Bs[kq + 0][row] = vb.x; Bs[kq + 1][row] = vb.y;
            Bs[kq + 2][row] = vb.z; Bs[kq + 3][row] = vb.w;
        } else {
            const int kk = t >> 4, nq = (t & 15) << 2;
            *(float4*)&Bs[kk][nq] = *(const float4*)(B + (size_t)(kt + kk) * ldb + n0 + nq);
        }
        __syncthreads();
        #pragma unroll
        for (int k = 0; k < 16; ++k) {
            const float4 av = *(const float4*)&As[k][ty << 2];
            const float4 bv = *(const float4*)&Bs[k][tx << 2];
            const float a[4] = {av.x, av.y, av.z, av.w};
            const float b[4] = {bv.x, bv.y, bv.z, bv.w};
            #pragma unroll
            for (int i = 0; i < 4; ++i)
                #pragma unroll
                for (int j = 0; j < 4; ++j)
                    acc[i][j] = fmaf(a[i], b[j], acc[i][j]);
        }
        __syncthreads();
    }

    #pragma unroll
    for (int i = 0; i < 4; ++i) {
        const int row = m0 + (ty << 2) + i;
        const int col = n0 + (tx << 2);
        float r[4];
        #pragma unroll
        for (int j = 0; j < 4; ++j) r[j] = acc[i][j];
        if (EPI == EPI_BIAS) {
            #pragma unroll
            for (int j = 0; j < 4; ++j) r[j] += bias[col + j];
        } else {
            const int c = ctype[row];
            #pragma unroll
            for (int j = 0; j < 4; ++j) r[j] += 0.1f * cemb[(size_t)c * E + col + j];
        }
        float4 rv; rv.x = r[0]; rv.y = r[1]; rv.z = r[2]; rv.w = r[3];
        *(float4*)&C[(size_t)row * ldc + col] = rv;
    }
}

// ---------------- fp32 [N][E] -> bf16 head-major [H][N][HD] -----------------
__global__ __launch_bounds__(256)
void conv_qk_k(const float* __restrict__ src, short* __restrict__ dst)
{
    const int f = blockIdx.x * 256 + threadIdx.x;    // N*E/4 threads
    const int n = f >> 7;
    const int e = (f & 127) << 2;
    const int h = e >> 6, d = e & 63;
    const float4 v = *(const float4*)(src + (size_t)n * E + e);
    short4 o; o.x = f2bf(v.x); o.y = f2bf(v.y); o.z = f2bf(v.z); o.w = f2bf(v.w);
    *(short4*)(dst + (size_t)h * N_NODES * HD + (size_t)n * HD + d) = o;
}

// ---------------- fp32 [N][E] -> bf16 transposed [H][HD][N] -----------------
__global__ __launch_bounds__(256)
void conv_vt_k(const float* __restrict__ src, short* __restrict__ dst)
{
    __shared__ short Ts[64][72];
    const int h  = blockIdx.x & 7;
    const int n0 = (blockIdx.x >> 3) * 64;
    const int t  = threadIdx.x;
    {
        const int r = t >> 2, s0 = (t & 3) * 16;
        #pragma unroll
        for (int i = 0; i < 4; ++i) {
            const float4 v = *(const float4*)(src + (size_t)(n0 + r) * E + h * HD + s0 + i * 4);
            Ts[r][s0 + i*4 + 0] = f2bf(v.x); Ts[r][s0 + i*4 + 1] = f2bf(v.y);
            Ts[r][s0 + i*4 + 2] = f2bf(v.z); Ts[r][s0 + i*4 + 3] = f2bf(v.w);
        }
    }
    __syncthreads();
    {
        const int d = t >> 2, ns = (t & 3) * 16;
        bf16x8 a, b;
        #pragma unroll
        for (int j = 0; j < 8; ++j) { a[j] = Ts[ns + j][d]; b[j] = Ts[ns + 8 + j][d]; }
        short* o = dst + (size_t)h * HD * N_NODES + (size_t)d * N_NODES + n0 + ns;
        *(bf16x8*)o = a;
        *(bf16x8*)(o + 8) = b;
    }
}

// ---------------- flash MHA: bf16 MFMA, online softmax ----------------------
// qh,kh: [H][N][HD] bf16 ; vt: [H][HD][N] bf16 ; o: [N][E] fp32
__global__ __launch_bounds__(256)
void flash_mha_k(const short* __restrict__ qh, const short* __restrict__ kh,
                 const short* __restrict__ vt, float* __restrict__ o)
{
    const int h  = blockIdx.y;
    const int q0 = blockIdx.x * 64;
    const int t  = threadIdx.x;
    const int wave = t >> 6, lane = t & 63;
    const int quad = lane >> 4, l16 = lane & 15;

    __shared__ __align__(16) short Kt[64][72];   // [key][d]
    __shared__ __align__(16) short Vs[64][72];   // [d][key]
    __shared__ __align__(16) short Pt[4][16][72];// per-wave [row][key]

    // Q fragments (A-layout: m=l16, k=quad*8+j), resident for whole kernel
    const short* qb = qh + ((size_t)h * N_NODES + q0 + wave * 16 + l16) * HD;
    bf16x8 aq0 = *(const bf16x8*)(qb + quad * 8);
    bf16x8 aq1 = *(const bf16x8*)(qb + 32 + quad * 8);

    f32x4 O[4] = {{0,0,0,0},{0,0,0,0},{0,0,0,0},{0,0,0,0}};
    float mr[4] = {-INFINITY,-INFINITY,-INFINITY,-INFINITY};
    float lr[4] = {0.f,0.f,0.f,0.f};

    const short* kb = kh + (size_t)h * N_NODES * HD;
    const short* vb = vt + (size_t)h * HD * N_NODES;

    for (int k0 = 0; k0 < N_NODES; k0 += 64) {
        __syncthreads();   // protect LDS reuse across iterations
        {
            const int r = t >> 3, s = (t & 7) * 8;
            #pragma unroll
            for (int it = 0; it < 2; ++it) {
                const int row = r + it * 32;
                *(bf16x8*)&Kt[row][s] = *(const bf16x8*)(kb + (size_t)(k0 + row) * HD + s);
                *(bf16x8*)&Vs[row][s] = *(const bf16x8*)(vb + (size_t)row * N_NODES + k0 + s);
            }
        }
        __syncthreads();

        // S = (Q K^T) * 0.125   (4 key-subtiles of 16)
        f32x4 S[4];
        #pragma unroll
        for (int c = 0; c < 4; ++c) {
            f32x4 acc = {0,0,0,0};
            bf16x8 b0 = *(const bf16x8*)&Kt[c * 16 + l16][quad * 8];
            bf16x8 b1 = *(const bf16x8*)&Kt[c * 16 + l16][32 + quad * 8];
            acc = __builtin_amdgcn_mfma_f32_16x16x32_bf16(aq0, b0, acc, 0, 0, 0);
            acc = __builtin_amdgcn_mfma_f32_16x16x32_bf16(aq1, b1, acc, 0, 0, 0);
            S[c] = acc * 0.125f;
        }

        // online softmax (row = quad*4 + r, col = c*16 + l16)
        float tm[4];
        #pragma unroll
        for (int r = 0; r < 4; ++r)
            tm[r] = fmaxf(fmaxf(S[0][r], S[1][r]), fmaxf(S[2][r], S[3][r]));
        #pragma unroll
        for (int off = 1; off <= 8; off <<= 1)
            #pragma unroll
            for (int r = 0; r < 4; ++r) tm[r] = fmaxf(tm[r], __shfl_xor(tm[r], off));

        float alpha[4], ps[4];
        #pragma unroll
        for (int r = 0; r < 4; ++r) {
            const float mn = fmaxf(mr[r], tm[r]);
            alpha[r] = __expf(mr[r] - mn);
            mr[r] = mn;
            ps[r] = 0.f;
        }
        #pragma unroll
        for (int c = 0; c < 4; ++c)
            #pragma unroll
            for (int r = 0; r < 4; ++r) {
                const float p = __expf(S[c][r] - mr[r]);
                S[c][r] = p;
                ps[r] += p;
            }
        #pragma unroll
        for (int off = 1; off <= 8; off <<= 1)
            #pragma unroll
            for (int r = 0; r < 4; ++r) ps[r] += __shfl_xor(ps[r], off);
        #pragma unroll
        for (int r = 0; r < 4; ++r) lr[r] = lr[r] * alpha[r] + ps[r];
        #pragma unroll
        for (int c = 0; c < 4; ++c)
            #pragma unroll
            for (int r = 0; r < 4; ++r) O[c][r] *= alpha[r];

        // P: C-layout -> LDS -> A-layout (intra-wave, no barrier needed)
        #pragma unroll
        for (int c = 0; c < 4; ++c)
            #pragma unroll
            for (int r = 0; r < 4; ++r)
                Pt[wave][quad * 4 + r][c * 16 + l16] = f2bf(S[c][r]);

        bf16x8 pf0 = *(const bf16x8*)&Pt[wave][l16][quad * 8];
        bf16x8 pf1 = *(const bf16x8*)&Pt[wave][l16][32 + quad * 8];
        #pragma unroll
        for (int c = 0; c < 4; ++c) {
            bf16x8 bv0 = *(const bf16x8*)&Vs[c * 16 + l16][quad * 8];
            bf16x8 bv1 = *(const bf16x8*)&Vs[c * 16 + l16][32 + quad * 8];
            O[c] = __builtin_amdgcn_mfma_f32_16x16x32_bf16(pf0, bv0, O[c], 0, 0, 0);
            O[c] = __builtin_amdgcn_mfma_f32_16x16x32_bf16(pf1, bv1, O[c], 0, 0, 0);
        }
    }

    float inv[4];
    #pragma unroll
    for (int r = 0; r < 4; ++r) inv[r] = 1.0f / lr[r];
    #pragma unroll
    for (int c = 0; c < 4; ++c)
        #pragma unroll
        for (int r = 0; r < 4; ++r) {
            const int row = q0 + wave * 16 + quad * 4 + r;
            o[(size_t)row * E + h * HD + c * 16 + l16] = O[c][r] * inv[r];
        }
}

// ---------------- edge utilities -------------------------------------------
__global__ __launch_bounds__(256)
void mask_build_k(const int* __restrict__ ei, unsigned* __restrict__ mask)
{
    const int i = blockIdx.x * 256 + threadIdx.x;
    const int r = ei[i];
    const int c = ei[NEDGE + i];
    atomicOr(&mask[(size_t)r * (N_NODES / 32) + (c >> 5)], 1u << (c & 31));
}

__device__ inline float waveMax(float v) {
    #pragma unroll
    for (int o = 32; o; o >>= 1) v = fmaxf(v, __shfl_xor(v, o));
    return v;
}
__device__ inline float waveSum(float v) {
    #pragma unroll
    for (int o = 32; o; o >>= 1) v += __shfl_xor(v, o);
    return v;
}

// One block per row: zero the row, enumerate edge columns from the bitmask
// (dedup), fp32 dot(Q[row], K[col]) per edge, exact softmax over edges,
// scatter p, accumulate entropy. Masked entries are exactly 0 (matches fp32
// exp(-1e9 - m) underflow in the reference).
__global__ __launch_bounds__(256)
void edge_attn_k(const float* __restrict__ Q, const float* __restrict__ Km,
                 const unsigned* __restrict__ mask, float* __restrict__ attn,
                 float* __restrict__ entAcc)
{
    const int row = blockIdx.x;
    const int t = threadIdx.x;
    const int wave = t >> 6, lane = t & 63;
    const size_t rowbase = (size_t)row * N_NODES;

    __shared__ float qrow[E];
    __shared__ int cols[MAXE];
    __shared__ float sc[MAXE];
    __shared__ int cnt;
    __shared__ float red[4];

    // zero the output row
    {
        const float4 z = {0.f, 0.f, 0.f, 0.f};
        #pragma unroll
        for (int j = 0; j < 4; ++j)
            *(float4*)&attn[rowbase + j * 1024 + t * 4] = z;
    }
    qrow[t] = Q[(size_t)row * E + t];
    qrow[256 + t] = Q[(size_t)row * E + 256 + t];
    if (t == 0) cnt = 0;
    __syncthreads();

    if (t < 128) {
        unsigned w = mask[(size_t)row * (N_NODES / 32) + t];
        while (w) {
            const int b = __ffs(w) - 1;
            w &= w - 1;
            const int idx = atomicAdd(&cnt, 1);
            cols[idx] = t * 32 + b;
        }
    }
    __syncthreads();
    const int nE = cnt;

    if (nE == 0) {   // uniform softmax row (unreachable for this input, but exact)
        const float p = 1.0f / 4096.0f;
        for (int j = t; j < N_NODES; j += 256) attn[rowbase + j] = p;
        if (t == 0) atomicAdd(entAcc, -4096.f * p * logf(p + 1e-10f));
        return;
    }

    // scores: one wave per edge
    const float scale = 0.044194173824159216f;   // 1/sqrt(512)
    for (int e = wave; e < nE; e += 4) {
        const float* kr = Km + (size_t)cols[e] * E;
        float acc = 0.f;
        #pragma unroll
        for (int i = 0; i < 2; ++i) {
            const float4 kv = *(const float4*)(kr + i * 256 + lane * 4);
            const float4 qv = *(const float4*)(&qrow[i * 256 + lane * 4]);
            acc += kv.x * qv.x + kv.y * qv.y + kv.z * qv.z + kv.w * qv.w;
        }
        acc = waveSum(acc);
        if (lane == 0) sc[e] = acc * scale;
    }
    __syncthreads();

    // softmax over the nE scores
    float lm = -3.4e38f;
    for (int e = t; e < nE; e += 256) lm = fmaxf(lm, sc[e]);
    lm = waveMax(lm);
    if (lane == 0) red[wave] = lm;
    __syncthreads();
    const float m = fmaxf(fmaxf(red[0], red[1]), fmaxf(red[2], red[3]));
    __syncthreads();

    float ls = 0.f;
    for (int e = t; e < nE; e += 256) ls += expf(sc[e] - m);
    ls = waveSum(ls);
    if (lane == 0) red[wave] = ls;
    __syncthreads();
    const float inv = 1.0f / (red[0] + red[1] + red[2] + red[3]);
    __syncthreads();

    float ent = 0.f;
    for (int e = t; e < nE; e += 256) {
        const float p = expf(sc[e] - m) * inv;
        attn[rowbase + cols[e]] = p;
        ent -= p * logf(p + 1e-10f);
    }
    ent = waveSum(ent);
    if (lane == 0) red[wave] = ent;
    __syncthreads();
    if (t == 0) atomicAdd(entAcc, red[0] + red[1] + red[2] + red[3]);
}

__global__ __launch_bounds__(256)
void phase_k(const float* __restrict__ Q, const float* __restrict__ K,
             float* __restrict__ out)
{
    const size_t i = (size_t)blockIdx.x * 256 + threadIdx.x;
    out[i] = atan2f(K[i], Q[i]);
}

__global__ void coh_k(const float* __restrict__ ent, float* __restrict__ out)
{
    out[0] = 1.0f - ent[0] / logf(4096.0f);
}

// ---------------------------------------------------------------------------
extern "C" void kernel_launch(void* const* d_in, const int* in_sizes, int n_in,
                              void* d_out, int out_size, void* d_ws, size_t ws_size,
                              hipStream_t stream)
{
    const float* x    = (const float*)d_in[0];
    const int*   ei   = (const int*)  d_in[1];
    const int*   ct   = (const int*)  d_in[2];
    const float* Wq   = (const float*)d_in[3];
    const float* bq   = (const float*)d_in[4];
    const float* Wk   = (const float*)d_in[5];
    const float* bk   = (const float*)d_in[6];
    const float* Wv   = (const float*)d_in[7];
    const float* bv   = (const float*)d_in[8];
    const float* bio  = (const float*)d_in[9];
    const float* cemb = (const float*)d_in[10];
    const float* ipw  = (const float*)d_in[11];
    const float* ipb  = (const float*)d_in[12];
    const float* ow   = (const float*)d_in[13];
    const float* ob   = (const float*)d_in[14];

    const size_t NE = (size_t)N_NODES * E;
    float* bufA = (float*)d_ws;              // Q0 -> q(fp32) -> vt(bf16)
    float* bufB = bufA + NE;                 // K0 -> k(fp32) -> o(MHA out)
    float* bufC = bufB + NE;                 // V  -> qh+kh (bf16)
    float* bufD = bufC + NE;                 // Q (post-bio, fp32, kept)
    float* bufE = bufD + NE;                 // K (post-bio, fp32, kept)
    unsigned* mask = (unsigned*)(bufE + NE); // 2 MB
    float* entAcc  = (float*)(mask + (size_t)N_NODES * (N_NODES / 32));

    float* outAttended = (float*)d_out;
    float* outAttn  = outAttended + NE;
    float* outPhase = outAttn + (size_t)N_NODES * N_NODES;
    float* outCoh   = outPhase + NE;
    float* vScratch = outPhase;              // v(fp32) until phase is written

    short* qh = (short*)bufC;                // [H][N][HD] bf16, 4 MB
    short* kh = qh + NE;                     // 4 MB (bufC is 8 MB)
    short* vt = (short*)bufA;                // [H][HD][N] bf16, 4 MB

    const dim3 blk(256);
    const dim3 gProj(E / 64, N_NODES / 64, 1);

    hipMemsetAsync(mask, 0, (size_t)N_NODES * (N_NODES / 32) * sizeof(unsigned), stream);
    hipMemsetAsync(entAcc, 0, sizeof(float), stream);
    mask_build_k<<<dim3(NEDGE / 256), blk, 0, stream>>>(ei, mask);

    // Q0/K0/V projections (fp32)
    gemm_k<true, EPI_BIAS><<<gProj, blk, 0, stream>>>(x, DIN, Wq, DIN, bufA, E, DIN, bq, nullptr, nullptr);
    gemm_k<true, EPI_BIAS><<<gProj, blk, 0, stream>>>(x, DIN, Wk, DIN, bufB, E, DIN, bk, nullptr, nullptr);
    gemm_k<true, EPI_BIAS><<<gProj, blk, 0, stream>>>(x, DIN, Wv, DIN, bufC, E, DIN, bv, nullptr, nullptr);

    // bio mixing + cell-emb (fp32 — feeds phase/atan2, precision-critical)
    gemm_k<false, EPI_CE><<<gProj, blk, 0, stream>>>(bufA, E, bio, E, bufD, E, E, nullptr, cemb, ct);
    gemm_k<true,  EPI_CE><<<gProj, blk, 0, stream>>>(bufB, E, bio, E, bufE, E, E, nullptr, cemb, ct);

    // in_proj q/k/v (fp32)
    gemm_k<true, EPI_BIAS><<<gProj, blk, 0, stream>>>(bufD, E, ipw,                 E, bufA,     E, E, ipb,         nullptr, nullptr);
    gemm_k<true, EPI_BIAS><<<gProj, blk, 0, stream>>>(bufE, E, ipw + (size_t)E*E,   E, bufB,     E, E, ipb + E,     nullptr, nullptr);
    gemm_k<true, EPI_BIAS><<<gProj, blk, 0, stream>>>(bufC, E, ipw + (size_t)2*E*E, E, vScratch, E, E, ipb + 2*E,   nullptr, nullptr);

    // bf16 head-major conversions
    conv_qk_k<<<dim3((unsigned)(NE / 4 / 256)), blk, 0, stream>>>(bufA, qh);
    conv_qk_k<<<dim3((unsigned)(NE / 4 / 256)), blk, 0, stream>>>(bufB, kh);
    conv_vt_k<<<dim3(512), blk, 0, stream>>>(vScratch, vt);

    // fused MHA (bf16 MFMA, online softmax) -> o in bufB
    flash_mha_k<<<dim3(N_NODES / 64, NH), blk, 0, stream>>>(qh, kh, vt, bufB);

    // attended = o @ out_w^T + out_b
    gemm_k<true, EPI_BIAS><<<gProj, blk, 0, stream>>>(bufB, E, ow, E, outAttended, E, E, ob, nullptr, nullptr);

    // phase = atan2(K, Q)  (overwrites vScratch region)
    phase_k<<<dim3((unsigned)(NE / 256)), blk, 0, stream>>>(bufD, bufE, outPhase);

    // edge-sparse graph attention + entropy
    edge_attn_k<<<dim3(N_NODES), blk, 0, stream>>>(bufD, bufE, mask, outAttn, entAcc);

    coh_k<<<1, 1, 0, stream>>>(entAcc, outCoh);
}

// Round 3
// 398.488 us; speedup vs baseline: 4.3262x; 1.5608x over previous
//
#include <hip/hip_runtime.h>
#include <hip/hip_bf16.h>
#include <math.h>

#define N_NODES 4096
#define DIN     256
#define E       512
#define NH      8
#define HD      64
#define NEDGE   131072
#define MAXE    1024

typedef short bf16x8 __attribute__((ext_vector_type(8)));
typedef float f32x4  __attribute__((ext_vector_type(4)));

__device__ inline short f2bf(float f) {
    __hip_bfloat16 h = __float2bfloat16(f);   // RNE
    return __builtin_bit_cast(short, h);
}
__device__ inline float bfbits2f(short s) {
    return __bfloat162float(__builtin_bit_cast(__hip_bfloat16, s));
}
__device__ inline void dec2(float f, short& h, short& l) {
    h = f2bf(f);
    l = f2bf(f - bfbits2f(h));
}

// ---------------------------------------------------------------------------
// fp32 512x512 transpose (for bio^T)
__global__ __launch_bounds__(256)
void tr512_k(const float* __restrict__ in, float* __restrict__ out)
{
    __shared__ float Ts[64][65];
    const int x0 = blockIdx.x * 64, y0 = blockIdx.y * 64;
    const int c = threadIdx.x & 63, r0 = threadIdx.x >> 6;
    #pragma unroll
    for (int i = 0; i < 16; ++i) {
        const int r = i * 4 + r0;
        Ts[r][c] = in[(size_t)(y0 + r) * E + x0 + c];
    }
    __syncthreads();
    #pragma unroll
    for (int i = 0; i < 16; ++i) {
        const int r = i * 4 + r0;
        out[(size_t)(x0 + r) * E + y0 + c] = Ts[c][r];
    }
}

// ---------------------------------------------------------------------------
// fp32 NN GEMM for effective weights: C[512x256] = A[512x512] @ B[512x256],
// z selects (bioT@Wq | bio@Wk | wv_i@Wv); output split-decomposed to bf16 hi/lo
// at rows z*512 of Wt[1536][256].
__global__ __launch_bounds__(256)
void prep_gemm_k(const float* __restrict__ bio, const float* __restrict__ bioT,
                 const float* __restrict__ ipw,
                 const float* __restrict__ Wq, const float* __restrict__ Wk,
                 const float* __restrict__ Wv,
                 short* __restrict__ Whi, short* __restrict__ Wlo)
{
    const int z = blockIdx.z;
    const float* A = (z == 0) ? bioT : (z == 1) ? bio : (ipw + (size_t)2 * E * E);
    const float* B = (z == 0) ? Wq : (z == 1) ? Wk : Wv;

    __shared__ float As[16][68];
    __shared__ float Bs[16][68];

    const int t  = threadIdx.x;
    const int m0 = blockIdx.y * 64;
    const int n0 = blockIdx.x * 64;
    const int ty = t >> 4, tx = t & 15;

    float acc[4][4] = {{0.f}};

    for (int kt = 0; kt < E; kt += 16) {
        {
            const int row = t >> 2, kq = (t & 3) << 2;
            const float4 va = *(const float4*)(A + (size_t)(m0 + row) * E + kt + kq);
            As[kq + 0][row] = va.x; As[kq + 1][row] = va.y;
            As[kq + 2][row] = va.z; As[kq + 3][row] = va.w;
        }
        {
            const int kk = t >> 4, nq = (t & 15) << 2;
            *(float4*)&Bs[kk][nq] = *(const float4*)(B + (size_t)(kt + kk) * DIN + n0 + nq);
        }
        __syncthreads();
        #pragma unroll
        for (int k = 0; k < 16; ++k) {
            const float4 av = *(const float4*)&As[k][ty << 2];
            const float4 bv = *(const float4*)&Bs[k][tx << 2];
            const float a[4] = {av.x, av.y, av.z, av.w};
            const float b[4] = {bv.x, bv.y, bv.z, bv.w};
            #pragma unroll
            for (int i = 0; i < 4; ++i)
                #pragma unroll
                for (int j = 0; j < 4; ++j)
                    acc[i][j] = fmaf(a[i], b[j], acc[i][j]);
        }
        __syncthreads();
    }

    #pragma unroll
    for (int i = 0; i < 4; ++i) {
        const int row = z * E + m0 + (ty << 2) + i;
        const int col = n0 + (tx << 2);
        #pragma unroll
        for (int j = 0; j < 4; ++j) {
            short h, l;
            dec2(acc[i][j], h, l);
            Whi[(size_t)row * DIN + col + j] = h;
            Wlo[(size_t)row * DIN + col + j] = l;
        }
    }
}

// ---------------------------------------------------------------------------
// effective biases: beff[0..512)=bq@bio, [512..1024)=bk@bio^T, [1024..1536)=bv@wv_i^T+bv_i
__global__ __launch_bounds__(256)
void bias_prep_k(const float* __restrict__ bq, const float* __restrict__ bk,
                 const float* __restrict__ bv, const float* __restrict__ bio,
                 const float* __restrict__ ipw, const float* __restrict__ ipb,
                 float* __restrict__ beff)
{
    const int n = blockIdx.x * 256 + threadIdx.x;   // 1536
    float s = 0.f;
    if (n < 512) {
        for (int e = 0; e < E; ++e) s += bq[e] * bio[(size_t)e * E + n];
    } else if (n < 1024) {
        const int nn = n - 512;
        for (int e = 0; e < E; ++e) s += bk[e] * bio[(size_t)nn * E + e];
    } else {
        const int nn = n - 1024;
        const float* wvi = ipw + (size_t)2 * E * E + (size_t)nn * E;
        for (int e = 0; e < E; ++e) s += bv[e] * wvi[e];
        s += ipb[1024 + nn];
    }
    beff[n] = s;
}

// ---------------------------------------------------------------------------
// elementwise fp32 -> bf16 (count = grid*256*4)
__global__ __launch_bounds__(256)
void conv_b16_k(const float* __restrict__ src, short* __restrict__ dst)
{
    const size_t i = ((size_t)blockIdx.x * 256 + threadIdx.x) * 4;
    const float4 v = *(const float4*)(src + i);
    short4 o; o.x = f2bf(v.x); o.y = f2bf(v.y); o.z = f2bf(v.z); o.w = f2bf(v.w);
    *(short4*)(dst + i) = o;
}

// elementwise fp32 -> split bf16 hi/lo
__global__ __launch_bounds__(256)
void dec_split_k(const float* __restrict__ src, short* __restrict__ hi,
                 short* __restrict__ lo)
{
    const size_t i = ((size_t)blockIdx.x * 256 + threadIdx.x) * 4;
    const float4 v = *(const float4*)(src + i);
    short4 h, l;
    dec2(v.x, h.x, l.x); dec2(v.y, h.y, l.y);
    dec2(v.z, h.z, l.z); dec2(v.w, h.w, l.w);
    *(short4*)(hi + i) = h;
    *(short4*)(lo + i) = l;
}

// ---------------------------------------------------------------------------
// bf16 MFMA GEMM, NT: C[M][N] = A[M][K] @ B[N][K]^T. 128x128 tile, BK=64,
// XOR-swizzled LDS. SPLIT: A/B given as hi+lo pairs, 3-pass MFMA (~fp32 acc).
// EPI 0 (MAIN):  +beff[col]; cols<1024 also +0.1*ce -> Qf/Kf fp32 + Qbf/Kbf bf16;
//                cols>=1024 -> vbuf fp32.
// EPI 1 (HEAD):  z-select A/B/bias/dst; +bias; bf16 head-major [H][N][HD] out.
// EPI 2 (OUT):   +bias; fp32 out.
template<bool SPLIT, int EPI>
__global__ __launch_bounds__(256)
void mf_gemm_k(const short* __restrict__ Ah, const short* __restrict__ Al,
               const short* __restrict__ Bh, const short* __restrict__ Bl,
               int K,
               const float* __restrict__ beff, const float* __restrict__ cemb,
               const int* __restrict__ ctype,
               float* __restrict__ f32a, float* __restrict__ f32b,
               float* __restrict__ f32c,
               short* __restrict__ b16a, short* __restrict__ b16b)
{
    constexpr int NSL = SPLIT ? 2 : 1;
    __shared__ __align__(16) short As[NSL][128 * 64];
    __shared__ __align__(16) short Bs[NSL][128 * 64];

    const int t = threadIdx.x;
    const int w = t >> 6, lane = t & 63;
    const int quad = lane >> 4, l16 = lane & 15;
    const int m0 = blockIdx.y * 128, n0 = blockIdx.x * 128;
    const int mw = (w >> 1) * 64, nw = (w & 1) * 64;

    const short* Ause = Ah;
    const short* Buse = Bh;
    const float* biasu = beff;
    short* dstu = b16a;
    if (EPI == 1 && blockIdx.z == 1) {
        Ause = Al; Buse = Bh + (size_t)E * E; biasu = beff + E; dstu = b16b;
    }

    f32x4 acc[4][4];
    #pragma unroll
    for (int i = 0; i < 4; ++i)
        #pragma unroll
        for (int j = 0; j < 4; ++j) acc[i][j] = (f32x4){0.f, 0.f, 0.f, 0.f};

    for (int kt = 0; kt < K; kt += 64) {
        __syncthreads();
        #pragma unroll
        for (int it = 0; it < 4; ++it) {
            const int idx = it * 256 + t;            // 1024 chunks of 8 bf16
            const int row = idx >> 3, ch = idx & 7;
            const int lo = row * 64 + ((ch ^ (row & 7)) << 3);
            *(bf16x8*)&As[0][lo] = *(const bf16x8*)(Ause + (size_t)(m0 + row) * K + kt + ch * 8);
            *(bf16x8*)&Bs[0][lo] = *(const bf16x8*)(Buse + (size_t)(n0 + row) * K + kt + ch * 8);
            if (SPLIT) {
                *(bf16x8*)&As[1][lo] = *(const bf16x8*)(Al + (size_t)(m0 + row) * K + kt + ch * 8);
                *(bf16x8*)&Bs[1][lo] = *(const bf16x8*)(Bl + (size_t)(n0 + row) * K + kt + ch * 8);
            }
        }
        __syncthreads();

        #pragma unroll
        for (int kk = 0; kk < 2; ++kk) {
            bf16x8 af[4], bf_[4], afl[4], bfl[4];
            #pragma unroll
            for (int i = 0; i < 4; ++i) {
                const int lo = (mw + 16 * i + l16) * 64 + (((kk * 4 + quad) ^ (l16 & 7)) << 3);
                af[i] = *(const bf16x8*)&As[0][lo];
                if (SPLIT) afl[i] = *(const bf16x8*)&As[1][lo];
            }
            #pragma unroll
            for (int j = 0; j < 4; ++j) {
                const int lo = (nw + 16 * j + l16) * 64 + (((kk * 4 + quad) ^ (l16 & 7)) << 3);
                bf_[j] = *(const bf16x8*)&Bs[0][lo];
                if (SPLIT) bfl[j] = *(const bf16x8*)&Bs[1][lo];
            }
            #pragma unroll
            for (int i = 0; i < 4; ++i)
                #pragma unroll
                for (int j = 0; j < 4; ++j) {
                    acc[i][j] = __builtin_amdgcn_mfma_f32_16x16x32_bf16(af[i], bf_[j], acc[i][j], 0, 0, 0);
                    if (SPLIT) {
                        acc[i][j] = __builtin_amdgcn_mfma_f32_16x16x32_bf16(af[i], bfl[j], acc[i][j], 0, 0, 0);
                        acc[i][j] = __builtin_amdgcn_mfma_f32_16x16x32_bf16(afl[i], bf_[j], acc[i][j], 0, 0, 0);
                    }
                }
        }
    }

    #pragma unroll
    for (int i = 0; i < 4; ++i)
        #pragma unroll
        for (int r = 0; r < 4; ++r) {
            const int row = m0 + mw + 16 * i + quad * 4 + r;
            #pragma unroll
            for (int j = 0; j < 4; ++j) {
                const int col = n0 + nw + 16 * j + l16;
                float v = acc[i][j][r];
                if (EPI == 0) {
                    v += beff[col];
                    if (col < 1024) {
                        const int cc = col & 511;
                        v += 0.1f * cemb[(size_t)ctype[row] * E + cc];
                        if (col < 512) {
                            f32a[(size_t)row * E + cc] = v;
                            b16a[(size_t)row * E + cc] = f2bf(v);
                        } else {
                            f32b[(size_t)row * E + cc] = v;
                            b16b[(size_t)row * E + cc] = f2bf(v);
                        }
                    } else {
                        f32c[(size_t)row * E + (col - 1024)] = v;
                    }
                } else if (EPI == 1) {
                    v += biasu[col];
                    dstu[((size_t)(col >> 6) * N_NODES + row) * HD + (col & 63)] = f2bf(v);
                } else {
                    v += biasu[col];
                    f32a[(size_t)row * E + col] = v;
                }
            }
        }
}

// ---------------------------------------------------------------------------
// fp32 [N][E] -> bf16 transposed [H][HD][N]
__global__ __launch_bounds__(256)
void conv_vt_k(const float* __restrict__ src, short* __restrict__ dst)
{
    __shared__ short Ts[64][72];
    const int h  = blockIdx.x & 7;
    const int n0 = (blockIdx.x >> 3) * 64;
    const int t  = threadIdx.x;
    {
        const int r = t >> 2, s0 = (t & 3) * 16;
        #pragma unroll
        for (int i = 0; i < 4; ++i) {
            const float4 v = *(const float4*)(src + (size_t)(n0 + r) * E + h * HD + s0 + i * 4);
            Ts[r][s0 + i*4 + 0] = f2bf(v.x); Ts[r][s0 + i*4 + 1] = f2bf(v.y);
            Ts[r][s0 + i*4 + 2] = f2bf(v.z); Ts[r][s0 + i*4 + 3] = f2bf(v.w);
        }
    }
    __syncthreads();
    {
        const int d = t >> 2, ns = (t & 3) * 16;
        bf16x8 a, b;
        #pragma unroll
        for (int j = 0; j < 8; ++j) { a[j] = Ts[ns + j][d]; b[j] = Ts[ns + 8 + j][d]; }
        short* o = dst + (size_t)h * HD * N_NODES + (size_t)d * N_NODES + n0 + ns;
        *(bf16x8*)o = a;
        *(bf16x8*)(o + 8) = b;
    }
}

// ---------------------------------------------------------------------------
// flash MHA, S^T formulation, key-split 2, swizzled LDS.
// qh,kh: [H][N][HD] bf16 ; vt: [H][HD][N] bf16
// Opart: [2][H][N][HD] fp32 (unnormalized), Mpart/Lpart: [2][H][N]
__global__ __launch_bounds__(256)
void flash_mha_k(const short* __restrict__ qh, const short* __restrict__ kh,
                 const short* __restrict__ vt, float* __restrict__ Opart,
                 float* __restrict__ Mpart, float* __restrict__ Lpart)
{
    const int h = blockIdx.y, z = blockIdx.z;
    const int q0 = blockIdx.x * 64;
    const int t = threadIdx.x, wave = t >> 6, lane = t & 63;
    const int quad = lane >> 4, l16 = lane & 15;
    const int sw = l16 & 7;

    __shared__ __align__(16) short Kt[64 * 64];
    __shared__ __align__(16) short Vs[64 * 64];
    __shared__ __align__(16) short Pt[4][16 * 64];

    const short* qb = qh + ((size_t)h * N_NODES + q0 + wave * 16 + l16) * HD;
    const bf16x8 aq0 = *(const bf16x8*)(qb + quad * 8);
    const bf16x8 aq1 = *(const bf16x8*)(qb + 32 + quad * 8);

    f32x4 O[4];
    #pragma unroll
    for (int c = 0; c < 4; ++c) O[c] = (f32x4){0.f, 0.f, 0.f, 0.f};
    float mr = -INFINITY, lr = 0.f;

    const short* kb = kh + (size_t)h * N_NODES * HD;
    const short* vb = vt + (size_t)h * HD * N_NODES;
    const int c0 = (quad ^ sw) << 3;
    const int c1 = c0 ^ 32;

    const int kbeg = z * (N_NODES / 2);
    for (int k0 = kbeg; k0 < kbeg + N_NODES / 2; k0 += 64) {
        __syncthreads();
        #pragma unroll
        for (int it = 0; it < 2; ++it) {
            const int idx = it * 256 + t;
            const int row = idx >> 3, ch = idx & 7;
            const int lo = row * 64 + ((ch ^ (row & 7)) << 3);
            *(bf16x8*)&Kt[lo] = *(const bf16x8*)(kb + (size_t)(k0 + row) * HD + ch * 8);
            *(bf16x8*)&Vs[lo] = *(const bf16x8*)(vb + (size_t)row * N_NODES + k0 + ch * 8);
        }
        __syncthreads();

        // S^T = (K Q^T) * 0.125 : rows = keys, cols = queries (this lane: query l16)
        f32x4 S[4];
        #pragma unroll
        for (int c = 0; c < 4; ++c) {
            const int rb = (16 * c + l16) * 64;
            const bf16x8 kf0 = *(const bf16x8*)&Kt[rb + c0];
            const bf16x8 kf1 = *(const bf16x8*)&Kt[rb + c1];
            f32x4 a = {0.f, 0.f, 0.f, 0.f};
            a = __builtin_amdgcn_mfma_f32_16x16x32_bf16(kf0, aq0, a, 0, 0, 0);
            a = __builtin_amdgcn_mfma_f32_16x16x32_bf16(kf1, aq1, a, 0, 0, 0);
            S[c] = a * 0.125f;
        }

        // per-query (l16) online softmax: in-lane over 16 keys + 2 shuffles
        float tmax = S[0][0];
        #pragma unroll
        for (int c = 0; c < 4; ++c)
            #pragma unroll
            for (int r = 0; r < 4; ++r) tmax = fmaxf(tmax, S[c][r]);
        tmax = fmaxf(tmax, __shfl_xor(tmax, 16));
        tmax = fmaxf(tmax, __shfl_xor(tmax, 32));

        const float mn = fmaxf(mr, tmax);
        const float alpha = __expf(mr - mn);
        mr = mn;
        float ps = 0.f;
        #pragma unroll
        for (int c = 0; c < 4; ++c)
            #pragma unroll
            for (int r = 0; r < 4; ++r) {
                const float p = __expf(S[c][r] - mn);
                S[c][r] = p;
                ps += p;
            }
        ps += __shfl_xor(ps, 16);
        ps += __shfl_xor(ps, 32);
        lr = lr * alpha + ps;

        // O rows are queries quad*4+r -> fetch their alphas (lane l16'=quad*4+r)
        float arow[4];
        #pragma unroll
        for (int r = 0; r < 4; ++r)
            arow[r] = __shfl(alpha, (lane & 48) | (((lane >> 2) & 12) + r));
        #pragma unroll
        for (int c = 0; c < 4; ++c)
            #pragma unroll
            for (int r = 0; r < 4; ++r) O[c][r] *= arow[r];

        // P[query][key] to LDS (swizzled), read back as A-fragments
        #pragma unroll
        for (int c = 0; c < 4; ++c)
            #pragma unroll
            for (int r = 0; r < 4; ++r) {
                const int col = 16 * c + quad * 4 + r;
                Pt[wave][l16 * 64 + (((col >> 3) ^ sw) << 3) + (col & 7)] = f2bf(S[c][r]);
            }
        const bf16x8 pf0 = *(const bf16x8*)&Pt[wave][l16 * 64 + c0];
        const bf16x8 pf1 = *(const bf16x8*)&Pt[wave][l16 * 64 + c1];
        #pragma unroll
        for (int c = 0; c < 4; ++c) {
            const int rb = (16 * c + l16) * 64;
            const bf16x8 vf0 = *(const bf16x8*)&Vs[rb + c0];
            const bf16x8 vf1 = *(const bf16x8*)&Vs[rb + c1];
            O[c] = __builtin_amdgcn_mfma_f32_16x16x32_bf16(pf0, vf0, O[c], 0, 0, 0);
            O[c] = __builtin_amdgcn_mfma_f32_16x16x32_bf16(pf1, vf1, O[c], 0, 0, 0);
        }
    }

    const size_t zb = ((size_t)z * NH + h) * N_NODES;
    #pragma unroll
    for (int c = 0; c < 4; ++c)
        #pragma unroll
        for (int r = 0; r < 4; ++r)
            Opart[(zb + q0 + wave * 16 + quad * 4 + r) * HD + 16 * c + l16] = O[c][r];
    if (quad == 0) {
        Mpart[zb + q0 + wave * 16 + l16] = mr;
        Lpart[zb + q0 + wave * 16 + l16] = lr;
    }
}

// combine the two key-split halves -> o (bf16 [N][E])
__global__ __launch_bounds__(256)
void combine_k(const float* __restrict__ Opart, const float* __restrict__ Mp,
               const float* __restrict__ Lp, short* __restrict__ obf)
{
    const int idx = blockIdx.x * 256 + threadIdx.x;   // N*E/4 threads
    const int e4 = idx * 4;
    const int q = e4 >> 9;
    const int col = e4 & 511;
    const int h = col >> 6, d = col & 63;
    const size_t b0 = (size_t)h * N_NODES + q;
    const size_t b1 = (size_t)NH * N_NODES + b0;
    const float m0 = Mp[b0], m1 = Mp[b1];
    const float l0 = Lp[b0], l1 = Lp[b1];
    const float M = fmaxf(m0, m1);
    const float w0 = __expf(m0 - M), w1 = __expf(m1 - M);
    const float inv = 1.0f / (w0 * l0 + w1 * l1);
    const float4 o0 = *(const float4*)&Opart[b0 * HD + d];
    const float4 o1 = *(const float4*)&Opart[b1 * HD + d];
    short4 o;
    o.x = f2bf((w0 * o0.x + w1 * o1.x) * inv);
    o.y = f2bf((w0 * o0.y + w1 * o1.y) * inv);
    o.z = f2bf((w0 * o0.z + w1 * o1.z) * inv);
    o.w = f2bf((w0 * o0.w + w1 * o1.w) * inv);
    *(short4*)&obf[(size_t)q * E + col] = o;
}

// ---------------------------------------------------------------------------
__global__ __launch_bounds__(256)
void mask_build_k(const int* __restrict__ ei, unsigned* __restrict__ mask)
{
    const int i = blockIdx.x * 256 + threadIdx.x;
    const int r = ei[i];
    const int c = ei[NEDGE + i];
    atomicOr(&mask[(size_t)r * (N_NODES / 32) + (c >> 5)], 1u << (c & 31));
}

__device__ inline float waveMax(float v) {
    #pragma unroll
    for (int o = 32; o; o >>= 1) v = fmaxf(v, __shfl_xor(v, o));
    return v;
}
__device__ inline float waveSum(float v) {
    #pragma unroll
    for (int o = 32; o; o >>= 1) v += __shfl_xor(v, o);
    return v;
}

__global__ __launch_bounds__(256)
void edge_attn_k(const float* __restrict__ Q, const float* __restrict__ Km,
                 const unsigned* __restrict__ mask, float* __restrict__ attn,
                 float* __restrict__ entAcc)
{
    const int row = blockIdx.x;
    const int t = threadIdx.x;
    const int wave = t >> 6, lane = t & 63;
    const size_t rowbase = (size_t)row * N_NODES;

    __shared__ float qrow[E];
    __shared__ int cols[MAXE];
    __shared__ float sc[MAXE];
    __shared__ int cnt;
    __shared__ float red[4];

    {
        const float4 zv = {0.f, 0.f, 0.f, 0.f};
        #pragma unroll
        for (int j = 0; j < 4; ++j)
            *(float4*)&attn[rowbase + j * 1024 + t * 4] = zv;
    }
    qrow[t] = Q[(size_t)row * E + t];
    qrow[256 + t] = Q[(size_t)row * E + 256 + t];
    if (t == 0) cnt = 0;
    __syncthreads();

    if (t < 128) {
        unsigned wm = mask[(size_t)row * (N_NODES / 32) + t];
        while (wm) {
            const int b = __ffs(wm) - 1;
            wm &= wm - 1;
            const int idx = atomicAdd(&cnt, 1);
            cols[idx] = t * 32 + b;
        }
    }
    __syncthreads();
    const int nE = cnt;

    if (nE == 0) {
        const float p = 1.0f / 4096.0f;
        for (int j = t; j < N_NODES; j += 256) attn[rowbase + j] = p;
        if (t == 0) atomicAdd(entAcc, -4096.f * p * logf(p + 1e-10f));
        return;
    }

    const float scale = 0.044194173824159216f;   // 1/sqrt(512)
    for (int e = wave; e < nE; e += 4) {
        const float* kr = Km + (size_t)cols[e] * E;
        float acc = 0.f;
        #pragma unroll
        for (int i = 0; i < 2; ++i) {
            const float4 kv = *(const float4*)(kr + i * 256 + lane * 4);
            const float4 qv = *(const float4*)(&qrow[i * 256 + lane * 4]);
            acc += kv.x * qv.x + kv.y * qv.y + kv.z * qv.z + kv.w * qv.w;
        }
        acc = waveSum(acc);
        if (lane == 0) sc[e] = acc * scale;
    }
    __syncthreads();

    float lm = -3.4e38f;
    for (int e = t; e < nE; e += 256) lm = fmaxf(lm, sc[e]);
    lm = waveMax(lm);
    if (lane == 0) red[wave] = lm;
    __syncthreads();
    const float m = fmaxf(fmaxf(red[0], red[1]), fmaxf(red[2], red[3]));
    __syncthreads();

    float ls = 0.f;
    for (int e = t; e < nE; e += 256) ls += expf(sc[e] - m);
    ls = waveSum(ls);
    if (lane == 0) red[wave] = ls;
    __syncthreads();
    const float inv = 1.0f / (red[0] + red[1] + red[2] + red[3]);
    __syncthreads();

    float ent = 0.f;
    for (int e = t; e < nE; e += 256) {
        const float p = expf(sc[e] - m) * inv;
        attn[rowbase + cols[e]] = p;
        ent -= p * logf(p + 1e-10f);
    }
    ent = waveSum(ent);
    if (lane == 0) red[wave] = ent;
    __syncthreads();
    if (t == 0) atomicAdd(entAcc, red[0] + red[1] + red[2] + red[3]);
}

__global__ __launch_bounds__(256)
void phase_k(const float* __restrict__ Q, const float* __restrict__ K,
             float* __restrict__ out)
{
    const size_t i = (size_t)blockIdx.x * 256 + threadIdx.x;
    out[i] = atan2f(K[i], Q[i]);
}

__global__ void coh_k(const float* __restrict__ ent, float* __restrict__ out)
{
    out[0] = 1.0f - ent[0] / logf(4096.0f);
}

// ---------------------------------------------------------------------------
extern "C" void kernel_launch(void* const* d_in, const int* in_sizes, int n_in,
                              void* d_out, int out_size, void* d_ws, size_t ws_size,
                              hipStream_t stream)
{
    const float* x    = (const float*)d_in[0];
    const int*   ei   = (const int*)  d_in[1];
    const int*   ct   = (const int*)  d_in[2];
    const float* Wq   = (const float*)d_in[3];
    const float* bq   = (const float*)d_in[4];
    const float* Wk   = (const float*)d_in[5];
    const float* bk   = (const float*)d_in[6];
    const float* Wv   = (const float*)d_in[7];
    const float* bv   = (const float*)d_in[8];
    const float* bio  = (const float*)d_in[9];
    const float* cemb = (const float*)d_in[10];
    const float* ipw  = (const float*)d_in[11];
    const float* ipb  = (const float*)d_in[12];
    const float* ow   = (const float*)d_in[13];
    const float* ob   = (const float*)d_in[14];

    const size_t NE = (size_t)N_NODES * E;   // 2,097,152

    // ws: only what must survive until edge_attn/phase
    float* Qf = (float*)d_ws;                 // [4096][512] fp32
    float* Kf = Qf + NE;
    unsigned* mask = (unsigned*)(Kf + NE);    // 2 MB
    float* entAcc = (float*)(mask + (size_t)N_NODES * (N_NODES / 32));

    // outputs
    float* outAttended = (float*)d_out;                    // [4096,512]
    float* outAttn  = outAttended + NE;                    // [4096,4096]
    float* outPhase = outAttn + (size_t)N_NODES * N_NODES; // [4096,512]
    float* outCoh   = outPhase + NE;                       // scalar

    // scratch carved from the attn output region (dead until edge_attn, which
    // runs last) — float-slot offsets:
    float* Opart = outAttn;                                  // 4,194,304 f
    float* Mpart = outAttn + 4194304;                        // 65,536 f
    float* Lpart = outAttn + 4259840;                        // 65,536 f
    short* obf   = (short*)(outAttn + 4325376);              // 2M shorts
    short* vt    = (short*)(outAttn + 5373952);              // [H][HD][N]
    short* qh    = (short*)(outAttn + 6422528);              // [H][N][HD]
    short* kh    = (short*)(outAttn + 7471104);
    short* Qbf   = (short*)(outAttn + 8519680);              // [N][E]
    short* Kbf   = (short*)(outAttn + 9568256);
    short* xhi   = (short*)(outAttn + 10616832);             // [N][DIN]
    short* xlo   = (short*)(outAttn + 11141120);
    short* Wthi  = (short*)(outAttn + 11665408);             // [1536][256]
    short* Wtlo  = (short*)(outAttn + 11862016);
    short* ipwbf = (short*)(outAttn + 12058624);             // [1024][512]
    short* owbf  = (short*)(outAttn + 12320768);             // [512][512]
    float* bioT  = outAttn + 12451840;                       // [512][512] f32
    float* beff  = outAttn + 12713984;                       // [1536]
    float* vbuf  = outPhase;   // v fp32, dead before phase_k writes

    const dim3 blk(256);

    hipMemsetAsync(mask, 0, (size_t)N_NODES * (N_NODES / 32) * sizeof(unsigned), stream);
    hipMemsetAsync(entAcc, 0, sizeof(float), stream);
    mask_build_k<<<dim3(NEDGE / 256), blk, 0, stream>>>(ei, mask);

    // effective weights / biases
    tr512_k<<<dim3(8, 8), blk, 0, stream>>>(bio, bioT);
    prep_gemm_k<<<dim3(4, 8, 3), blk, 0, stream>>>(bio, bioT, ipw, Wq, Wk, Wv, Wthi, Wtlo);
    bias_prep_k<<<dim3(6), blk, 0, stream>>>(bq, bk, bv, bio, ipw, ipb, beff);

    // conversions
    dec_split_k<<<dim3(1024), blk, 0, stream>>>(x, xhi, xlo);
    conv_b16_k<<<dim3(512), blk, 0, stream>>>(ipw, ipwbf);   // wq_i|wk_i rows
    conv_b16_k<<<dim3(256), blk, 0, stream>>>(ow, owbf);

    // main fused GEMM: [Q|K|v] = x @ Weff^T (+ ce, beff) — split-bf16
    mf_gemm_k<true, 0><<<dim3(12, 32, 1), blk, 0, stream>>>(
        xhi, xlo, Wthi, Wtlo, DIN, beff, cemb, ct,
        Qf, Kf, vbuf, Qbf, Kbf);

    conv_vt_k<<<dim3(512), blk, 0, stream>>>(vbuf, vt);

    // in_proj q/k (plain bf16), bf16 head-major out
    mf_gemm_k<false, 1><<<dim3(4, 32, 2), blk, 0, stream>>>(
        Qbf, Kbf, ipwbf, nullptr, E, ipb, nullptr, nullptr,
        nullptr, nullptr, nullptr, qh, kh);

    // flash MHA (key-split 2) + combine
    flash_mha_k<<<dim3(N_NODES / 64, NH, 2), blk, 0, stream>>>(qh, kh, vt, Opart, Mpart, Lpart);
    combine_k<<<dim3((unsigned)(NE / 4 / 256)), blk, 0, stream>>>(Opart, Mpart, Lpart, obf);

    // attended = o @ out_w^T + out_b
    mf_gemm_k<false, 2><<<dim3(4, 32, 1), blk, 0, stream>>>(
        obf, nullptr, owbf, nullptr, E, ob, nullptr, nullptr,
        outAttended, nullptr, nullptr, nullptr, nullptr);

    // phase (overwrites vbuf region)
    phase_k<<<dim3((unsigned)(NE / 256)), blk, 0, stream>>>(Qf, Kf, outPhase);

    // edge-sparse graph attention + entropy (overwrites attn-region scratch)
    edge_attn_k<<<dim3(N_NODES), blk, 0, stream>>>(Qf, Kf, mask, outAttn, entAcc);

    coh_k<<<1, 1, 0, stream>>>(entAcc, outCoh);
}

// Round 5
// 394.630 us; speedup vs baseline: 4.3685x; 1.0098x over previous
//
#include <hip/hip_runtime.h>
#include <hip/hip_bf16.h>
#include <math.h>

#define N_NODES 4096
#define DIN     256
#define E       512
#define NH      8
#define HD      64
#define NEDGE   131072
#define MAXE    1024
#define LSC     0.180336880111120f   // 0.125 * log2(e)

typedef short bf16x8 __attribute__((ext_vector_type(8)));
typedef float f32x4  __attribute__((ext_vector_type(4)));

__device__ inline short f2bf(float f) {
    __hip_bfloat16 h = __float2bfloat16(f);   // RNE
    return __builtin_bit_cast(short, h);
}
__device__ inline float bfbits2f(short s) {
    return __bfloat162float(__builtin_bit_cast(__hip_bfloat16, s));
}
__device__ inline void dec2(float f, short& h, short& l) {
    h = f2bf(f);
    l = f2bf(f - bfbits2f(h));
}
__device__ inline unsigned packbf2(float a, float b) {
    return (unsigned)(unsigned short)f2bf(a) |
           ((unsigned)(unsigned short)f2bf(b) << 16);
}

// ---------------------------------------------------------------------------
// fp32 GEMM for effective weights: C[512x256], z: (bio^T@Wq | bio@Wk | wv_i@Wv)
// z=0 stages bio transposed on the fly. Output split-bf16 to Wt[1536][256].
__global__ __launch_bounds__(256)
void prep_gemm_k(const float* __restrict__ bio, const float* __restrict__ ipw,
                 const float* __restrict__ Wq, const float* __restrict__ Wk,
                 const float* __restrict__ Wv,
                 short* __restrict__ Whi, short* __restrict__ Wlo)
{
    const int z = blockIdx.z;
    const float* A = (z == 2) ? (ipw + (size_t)2 * E * E) : bio;
    const float* B = (z == 0) ? Wq : (z == 1) ? Wk : Wv;

    __shared__ float As[16][68];
    __shared__ float Bs[16][68];

    const int t  = threadIdx.x;
    const int m0 = blockIdx.y * 64;
    const int n0 = blockIdx.x * 64;
    const int ty = t >> 4, tx = t & 15;

    float acc[4][4] = {{0.f}};

    for (int kt = 0; kt < E; kt += 16) {
        if (z == 0) {   // As[k][m] = bio[k][m]  (A^T staging)
            const int kk = t >> 4, nq = (t & 15) << 2;
            *(float4*)&As[kk][nq] = *(const float4*)(A + (size_t)(kt + kk) * E + m0 + nq);
        } else {
            const int row = t >> 2, kq = (t & 3) << 2;
            const float4 va = *(const float4*)(A + (size_t)(m0 + row) * E + kt + kq);
            As[kq + 0][row] = va.x; As[kq + 1][row] = va.y;
            As[kq + 2][row] = va.z; As[kq + 3][row] = va.w;
        }
        {
            const int kk = t >> 4, nq = (t & 15) << 2;
            *(float4*)&Bs[kk][nq] = *(const float4*)(B + (size_t)(kt + kk) * DIN + n0 + nq);
        }
        __syncthreads();
        #pragma unroll
        for (int k = 0; k < 16; ++k) {
            const float4 av = *(const float4*)&As[k][ty << 2];
            const float4 bv = *(const float4*)&Bs[k][tx << 2];
            const float a[4] = {av.x, av.y, av.z, av.w};
            const float b[4] = {bv.x, bv.y, bv.z, bv.w};
            #pragma unroll
            for (int i = 0; i < 4; ++i)
                #pragma unroll
                for (int j = 0; j < 4; ++j)
                    acc[i][j] = fmaf(a[i], b[j], acc[i][j]);
        }
        __syncthreads();
    }

    #pragma unroll
    for (int i = 0; i < 4; ++i) {
        const int row = z * E + m0 + (ty << 2) + i;
        const int col = n0 + (tx << 2);
        #pragma unroll
        for (int j = 0; j < 4; ++j) {
            short h, l;
            dec2(acc[i][j], h, l);
            Whi[(size_t)row * DIN + col + j] = h;
            Wlo[(size_t)row * DIN + col + j] = l;
        }
    }
}

// ---------------------------------------------------------------------------
// merged conversions: x split-bf16 | ipw(q,k rows) bf16 | ow bf16 | beff
__global__ __launch_bounds__(256)
void conv_all_k(const float* __restrict__ x, const float* __restrict__ ipw,
                const float* __restrict__ ow,
                const float* __restrict__ bq, const float* __restrict__ bk,
                const float* __restrict__ bv, const float* __restrict__ bio,
                const float* __restrict__ ipb,
                short* __restrict__ xhi, short* __restrict__ xlo,
                short* __restrict__ ipwbf, short* __restrict__ owbf,
                float* __restrict__ beff)
{
    const int b = blockIdx.x, t = threadIdx.x;
    if (b < 1024) {                       // x: 1,048,576 elements, split hi/lo
        const size_t i = ((size_t)b * 256 + t) * 4;
        const float4 v = *(const float4*)(x + i);
        short4 h, l;
        dec2(v.x, h.x, l.x); dec2(v.y, h.y, l.y);
        dec2(v.z, h.z, l.z); dec2(v.w, h.w, l.w);
        *(short4*)(xhi + i) = h;
        *(short4*)(xlo + i) = l;
    } else if (b < 1536) {                // ipw rows 0..1024: 524,288 elements
        const size_t i = ((size_t)(b - 1024) * 256 + t) * 4;
        const float4 v = *(const float4*)(ipw + i);
        short4 o; o.x = f2bf(v.x); o.y = f2bf(v.y); o.z = f2bf(v.z); o.w = f2bf(v.w);
        *(short4*)(ipwbf + i) = o;
    } else if (b < 1792) {                // ow: 262,144 elements
        const size_t i = ((size_t)(b - 1536) * 256 + t) * 4;
        const float4 v = *(const float4*)(ow + i);
        short4 o; o.x = f2bf(v.x); o.y = f2bf(v.y); o.z = f2bf(v.z); o.w = f2bf(v.w);
        *(short4*)(owbf + i) = o;
    } else {                              // effective biases: 1536 values
        const int n = (b - 1792) * 256 + t;
        float s = 0.f;
        if (n < 512) {
            for (int e = 0; e < E; ++e) s += bq[e] * bio[(size_t)e * E + n];
        } else if (n < 1024) {
            const int nn = n - 512;
            for (int e = 0; e < E; ++e) s += bk[e] * bio[(size_t)nn * E + e];
        } else {
            const int nn = n - 1024;
            const float* wvi = ipw + (size_t)2 * E * E + (size_t)nn * E;
            for (int e = 0; e < E; ++e) s += bv[e] * wvi[e];
            s += ipb[1024 + nn];
        }
        beff[n] = s;
    }
}

// ---------------------------------------------------------------------------
// bf16 MFMA GEMM, NT: C[M][N] = A[M][K] @ B[N][K]^T. 128x128, BK=64, swizzled.
// EPI 0 (MAIN): +beff; cols<1024: +0.1*ce -> Qf/Kf fp32 + Qbf/Kbf bf16;
//               cols>=1024: v -> bf16 transposed [H][HD][N] (vt).
// EPI 1 (HEAD): z-select; +bias; bf16 head-major [H][N][HD].
// EPI 2 (OUT):  +bias; fp32.
template<bool SPLIT, int EPI>
__global__ __launch_bounds__(256)
void mf_gemm_k(const short* __restrict__ Ah, const short* __restrict__ Al,
               const short* __restrict__ Bh, const short* __restrict__ Bl,
               int K,
               const float* __restrict__ beff, const float* __restrict__ cemb,
               const int* __restrict__ ctype,
               float* __restrict__ f32a, float* __restrict__ f32b,
               short* __restrict__ b16a, short* __restrict__ b16b,
               short* __restrict__ b16c)
{
    constexpr int NSL = SPLIT ? 2 : 1;
    __shared__ __align__(16) short As[NSL][128 * 64];
    __shared__ __align__(16) short Bs[NSL][128 * 64];

    const int t = threadIdx.x;
    const int w = t >> 6, lane = t & 63;
    const int quad = lane >> 4, l16 = lane & 15;
    const int m0 = blockIdx.y * 128, n0 = blockIdx.x * 128;
    const int mw = (w >> 1) * 64, nw = (w & 1) * 64;

    const short* Ause = Ah;
    const short* Buse = Bh;
    const float* biasu = beff;
    short* dstu = b16a;
    if (EPI == 1 && blockIdx.z == 1) {
        Ause = Al; Buse = Bh + (size_t)E * E; biasu = beff + E; dstu = b16b;
    }

    f32x4 acc[4][4];
    #pragma unroll
    for (int i = 0; i < 4; ++i)
        #pragma unroll
        for (int j = 0; j < 4; ++j) acc[i][j] = (f32x4){0.f, 0.f, 0.f, 0.f};

    for (int kt = 0; kt < K; kt += 64) {
        __syncthreads();
        #pragma unroll
        for (int it = 0; it < 4; ++it) {
            const int idx = it * 256 + t;
            const int row = idx >> 3, ch = idx & 7;
            const int lo = row * 64 + ((ch ^ (row & 7)) << 3);
            *(bf16x8*)&As[0][lo] = *(const bf16x8*)(Ause + (size_t)(m0 + row) * K + kt + ch * 8);
            *(bf16x8*)&Bs[0][lo] = *(const bf16x8*)(Buse + (size_t)(n0 + row) * K + kt + ch * 8);
            if (SPLIT) {
                *(bf16x8*)&As[1][lo] = *(const bf16x8*)(Al + (size_t)(m0 + row) * K + kt + ch * 8);
                *(bf16x8*)&Bs[1][lo] = *(const bf16x8*)(Bl + (size_t)(n0 + row) * K + kt + ch * 8);
            }
        }
        __syncthreads();

        #pragma unroll
        for (int kk = 0; kk < 2; ++kk) {
            bf16x8 af[4], bf_[4], afl[4], bfl[4];
            #pragma unroll
            for (int i = 0; i < 4; ++i) {
                const int lo = (mw + 16 * i + l16) * 64 + (((kk * 4 + quad) ^ (l16 & 7)) << 3);
                af[i] = *(const bf16x8*)&As[0][lo];
                if (SPLIT) afl[i] = *(const bf16x8*)&As[1][lo];
            }
            #pragma unroll
            for (int j = 0; j < 4; ++j) {
                const int lo = (nw + 16 * j + l16) * 64 + (((kk * 4 + quad) ^ (l16 & 7)) << 3);
                bf_[j] = *(const bf16x8*)&Bs[0][lo];
                if (SPLIT) bfl[j] = *(const bf16x8*)&Bs[1][lo];
            }
            #pragma unroll
            for (int i = 0; i < 4; ++i)
                #pragma unroll
                for (int j = 0; j < 4; ++j) {
                    acc[i][j] = __builtin_amdgcn_mfma_f32_16x16x32_bf16(af[i], bf_[j], acc[i][j], 0, 0, 0);
                    if (SPLIT) {
                        acc[i][j] = __builtin_amdgcn_mfma_f32_16x16x32_bf16(af[i], bfl[j], acc[i][j], 0, 0, 0);
                        acc[i][j] = __builtin_amdgcn_mfma_f32_16x16x32_bf16(afl[i], bf_[j], acc[i][j], 0, 0, 0);
                    }
                }
        }
    }

    #pragma unroll
    for (int i = 0; i < 4; ++i) {
        const int row0 = m0 + mw + 16 * i + quad * 4;
        #pragma unroll
        for (int j = 0; j < 4; ++j) {
            const int col = n0 + nw + 16 * j + l16;
            if (EPI == 0 && col >= 1024) {   // v -> vt bf16 [H][HD][N], 4 rows packed
                const int hh = (col - 1024) >> 6, d = (col - 1024) & 63;
                short4 o;
                o.x = f2bf(acc[i][j][0] + beff[col]);
                o.y = f2bf(acc[i][j][1] + beff[col]);
                o.z = f2bf(acc[i][j][2] + beff[col]);
                o.w = f2bf(acc[i][j][3] + beff[col]);
                *(short4*)(b16c + ((size_t)hh * HD + d) * N_NODES + row0) = o;
                continue;
            }
            #pragma unroll
            for (int r = 0; r < 4; ++r) {
                const int row = row0 + r;
                float v = acc[i][j][r];
                if (EPI == 0) {
                    v += beff[col];
                    const int cc = col & 511;
                    v += 0.1f * cemb[(size_t)ctype[row] * E + cc];
                    if (col < 512) {
                        f32a[(size_t)row * E + cc] = v;
                        b16a[(size_t)row * E + cc] = f2bf(v);
                    } else {
                        f32b[(size_t)row * E + cc] = v;
                        b16b[(size_t)row * E + cc] = f2bf(v);
                    }
                } else if (EPI == 1) {
                    v += biasu[col];
                    dstu[((size_t)(col >> 6) * N_NODES + row) * HD + (col & 63)] = f2bf(v);
                } else {
                    v += biasu[col];
                    f32a[(size_t)row * E + col] = v;
                }
            }
        }
    }
}

// ---------------------------------------------------------------------------
// flash MHA, S^T formulation, key-split 2, double-buffered K/V, exp2 softmax.
// qh,kh: [H][N][HD] bf16 ; vt: [H][HD][N] bf16
// Opart: [2][H][N][HD] fp32 ; Mpart (log2-domain, pre-scaled), Lpart: [2][H][N]
__global__ __launch_bounds__(256)
void flash_mha_k(const short* __restrict__ qh, const short* __restrict__ kh,
                 const short* __restrict__ vt, float* __restrict__ Opart,
                 float* __restrict__ Mpart, float* __restrict__ Lpart)
{
    const int h = blockIdx.y, z = blockIdx.z;
    const int q0 = blockIdx.x * 64;
    const int t = threadIdx.x, wave = t >> 6, lane = t & 63;
    const int quad = lane >> 4, l16 = lane & 15;
    const int sw = l16 & 7;

    __shared__ __align__(16) short Kt[2][64 * 64];
    __shared__ __align__(16) short Vs[2][64 * 64];
    __shared__ __align__(16) short Pt[4][16 * 64];

    const short* qb = qh + ((size_t)h * N_NODES + q0 + wave * 16 + l16) * HD;
    const bf16x8 aq0 = *(const bf16x8*)(qb + quad * 8);
    const bf16x8 aq1 = *(const bf16x8*)(qb + 32 + quad * 8);

    f32x4 O[4];
    #pragma unroll
    for (int c = 0; c < 4; ++c) O[c] = (f32x4){0.f, 0.f, 0.f, 0.f};
    float mr = -INFINITY, lr = 0.f;

    const short* kb = kh + (size_t)h * N_NODES * HD;
    const short* vb = vt + (size_t)h * HD * N_NODES;
    const int c0 = (quad ^ sw) << 3;
    const int c1 = c0 ^ 32;

    // staging geometry: 2 chunks/thread
    int rows[2], chs[2], los[2];
    #pragma unroll
    for (int it = 0; it < 2; ++it) {
        const int idx = it * 256 + t;
        rows[it] = idx >> 3; chs[it] = idx & 7;
        los[it] = rows[it] * 64 + ((chs[it] ^ (rows[it] & 7)) << 3);
    }

    const int kbeg = z * (N_NODES / 2);
    bf16x8 pk[2], pv[2];
    #pragma unroll
    for (int it = 0; it < 2; ++it) {
        pk[it] = *(const bf16x8*)(kb + (size_t)(kbeg + rows[it]) * HD + chs[it] * 8);
        pv[it] = *(const bf16x8*)(vb + (size_t)rows[it] * N_NODES + kbeg + chs[it] * 8);
    }
    #pragma unroll
    for (int it = 0; it < 2; ++it) {
        *(bf16x8*)&Kt[0][los[it]] = pk[it];
        *(bf16x8*)&Vs[0][los[it]] = pv[it];
    }
    __syncthreads();

    const int NT = (N_NODES / 2) / 64;   // 32
    for (int i = 0; i < NT; ++i) {
        const int cur = i & 1;
        if (i + 1 < NT) {   // prefetch next tile into regs (overlaps compute)
            const int nxt = kbeg + (i + 1) * 64;
            #pragma unroll
            for (int it = 0; it < 2; ++it) {
                pk[it] = *(const bf16x8*)(kb + (size_t)(nxt + rows[it]) * HD + chs[it] * 8);
                pv[it] = *(const bf16x8*)(vb + (size_t)rows[it] * N_NODES + nxt + chs[it] * 8);
            }
        }

        // S^T = K Q^T (raw scores; scale folded into exp2)
        f32x4 S[4];
        #pragma unroll
        for (int c = 0; c < 4; ++c) {
            const int rb = (16 * c + l16) * 64;
            const bf16x8 kf0 = *(const bf16x8*)&Kt[cur][rb + c0];
            const bf16x8 kf1 = *(const bf16x8*)&Kt[cur][rb + c1];
            f32x4 a = {0.f, 0.f, 0.f, 0.f};
            a = __builtin_amdgcn_mfma_f32_16x16x32_bf16(kf0, aq0, a, 0, 0, 0);
            a = __builtin_amdgcn_mfma_f32_16x16x32_bf16(kf1, aq1, a, 0, 0, 0);
            S[c] = a;
        }

        // per-query (l16) online softmax in exp2 domain
        float tmax = S[0][0];
        #pragma unroll
        for (int c = 0; c < 4; ++c)
            #pragma unroll
            for (int r = 0; r < 4; ++r) tmax = fmaxf(tmax, S[c][r]);
        tmax = fmaxf(tmax, __shfl_xor(tmax, 16));
        tmax = fmaxf(tmax, __shfl_xor(tmax, 32));

        const float mn = fmaxf(mr, tmax);
        const float alpha = exp2f((mr - mn) * LSC);
        mr = mn;
        const float cc = -mn * LSC;
        float ps = 0.f;
        #pragma unroll
        for (int c = 0; c < 4; ++c)
            #pragma unroll
            for (int r = 0; r < 4; ++r) {
                const float p = exp2f(fmaf(S[c][r], LSC, cc));
                S[c][r] = p;
                ps += p;
            }
        ps += __shfl_xor(ps, 16);
        ps += __shfl_xor(ps, 32);
        lr = lr * alpha + ps;

        float arow[4];
        #pragma unroll
        for (int r = 0; r < 4; ++r)
            arow[r] = __shfl(alpha, (lane & 48) | (((lane >> 2) & 12) + r));
        #pragma unroll
        for (int c = 0; c < 4; ++c)
            #pragma unroll
            for (int r = 0; r < 4; ++r) O[c][r] *= arow[r];

        // P[query][key] -> LDS, packed b32 writes (keys quad*4+r are adjacent)
        #pragma unroll
        for (int c = 0; c < 4; ++c) {
            const int chunk = 2 * c + (quad >> 1);
            const int off = l16 * 64 + ((chunk ^ sw) << 3) + (quad & 1) * 4;
            *(unsigned*)&Pt[wave][off]     = packbf2(S[c][0], S[c][1]);
            *(unsigned*)&Pt[wave][off + 2] = packbf2(S[c][2], S[c][3]);
        }
        const bf16x8 pf0 = *(const bf16x8*)&Pt[wave][l16 * 64 + c0];
        const bf16x8 pf1 = *(const bf16x8*)&Pt[wave][l16 * 64 + c1];
        #pragma unroll
        for (int c = 0; c < 4; ++c) {
            const int rb = (16 * c + l16) * 64;
            const bf16x8 vf0 = *(const bf16x8*)&Vs[cur][rb + c0];
            const bf16x8 vf1 = *(const bf16x8*)&Vs[cur][rb + c1];
            O[c] = __builtin_amdgcn_mfma_f32_16x16x32_bf16(pf0, vf0, O[c], 0, 0, 0);
            O[c] = __builtin_amdgcn_mfma_f32_16x16x32_bf16(pf1, vf1, O[c], 0, 0, 0);
        }

        if (i + 1 < NT) {
            #pragma unroll
            for (int it = 0; it < 2; ++it) {
                *(bf16x8*)&Kt[cur ^ 1][los[it]] = pk[it];
                *(bf16x8*)&Vs[cur ^ 1][los[it]] = pv[it];
            }
        }
        __syncthreads();
    }

    const size_t zb = ((size_t)z * NH + h) * N_NODES;
    #pragma unroll
    for (int c = 0; c < 4; ++c)
        #pragma unroll
        for (int r = 0; r < 4; ++r)
            Opart[(zb + q0 + wave * 16 + quad * 4 + r) * HD + 16 * c + l16] = O[c][r];
    if (quad == 0) {
        Mpart[zb + q0 + wave * 16 + l16] = mr * LSC;   // log2 domain
        Lpart[zb + q0 + wave * 16 + l16] = lr;
    }
}

// combine the two key-split halves -> o (bf16 [N][E])
__global__ __launch_bounds__(256)
void combine_k(const float* __restrict__ Opart, const float* __restrict__ Mp,
               const float* __restrict__ Lp, short* __restrict__ obf)
{
    const int idx = blockIdx.x * 256 + threadIdx.x;
    const int e4 = idx * 4;
    const int q = e4 >> 9;
    const int col = e4 & 511;
    const int h = col >> 6, d = col & 63;
    const size_t b0 = (size_t)h * N_NODES + q;
    const size_t b1 = (size_t)NH * N_NODES + b0;
    const float m0 = Mp[b0], m1 = Mp[b1];
    const float l0 = Lp[b0], l1 = Lp[b1];
    const float M = fmaxf(m0, m1);
    const float w0 = exp2f(m0 - M), w1 = exp2f(m1 - M);
    const float inv = 1.0f / (w0 * l0 + w1 * l1);
    const float4 o0 = *(const float4*)&Opart[b0 * HD + d];
    const float4 o1 = *(const float4*)&Opart[b1 * HD + d];
    short4 o;
    o.x = f2bf((w0 * o0.x + w1 * o1.x) * inv);
    o.y = f2bf((w0 * o0.y + w1 * o1.y) * inv);
    o.z = f2bf((w0 * o0.z + w1 * o1.z) * inv);
    o.w = f2bf((w0 * o0.w + w1 * o1.w) * inv);
    *(short4*)&obf[(size_t)q * E + col] = o;
}

// ---------------------------------------------------------------------------
__global__ __launch_bounds__(256)
void mask_build_k(const int* __restrict__ ei, unsigned* __restrict__ mask)
{
    const int i = blockIdx.x * 256 + threadIdx.x;
    const int r = ei[i];
    const int c = ei[NEDGE + i];
    atomicOr(&mask[(size_t)r * (N_NODES / 32) + (c >> 5)], 1u << (c & 31));
}

__device__ inline float waveMax(float v) {
    #pragma unroll
    for (int o = 32; o; o >>= 1) v = fmaxf(v, __shfl_xor(v, o));
    return v;
}
__device__ inline float waveSum(float v) {
    #pragma unroll
    for (int o = 32; o; o >>= 1) v += __shfl_xor(v, o);
    return v;
}

__global__ __launch_bounds__(256)
void edge_attn_k(const float* __restrict__ Q, const float* __restrict__ Km,
                 const unsigned* __restrict__ mask, float* __restrict__ attn,
                 float* __restrict__ entAcc)
{
    const int row = blockIdx.x;
    const int t = threadIdx.x;
    const int wave = t >> 6, lane = t & 63;
    const size_t rowbase = (size_t)row * N_NODES;

    __shared__ float qrow[E];
    __shared__ int cols[MAXE];
    __shared__ float sc[MAXE];
    __shared__ int cnt;
    __shared__ float red[4];

    {
        const float4 zv = {0.f, 0.f, 0.f, 0.f};
        #pragma unroll
        for (int j = 0; j < 4; ++j)
            *(float4*)&attn[rowbase + j * 1024 + t * 4] = zv;
    }
    qrow[t] = Q[(size_t)row * E + t];
    qrow[256 + t] = Q[(size_t)row * E + 256 + t];
    if (t == 0) cnt = 0;
    __syncthreads();

    if (t < 128) {
        unsigned wm = mask[(size_t)row * (N_NODES / 32) + t];
        while (wm) {
            const int b = __ffs(wm) - 1;
            wm &= wm - 1;
            const int idx = atomicAdd(&cnt, 1);
            cols[idx] = t * 32 + b;
        }
    }
    __syncthreads();
    const int nE = cnt;

    if (nE == 0) {
        const float p = 1.0f / 4096.0f;
        for (int j = t; j < N_NODES; j += 256) attn[rowbase + j] = p;
        if (t == 0) atomicAdd(entAcc, -4096.f * p * logf(p + 1e-10f));
        return;
    }

    const float scale = 0.044194173824159216f;   // 1/sqrt(512)
    for (int e = wave; e < nE; e += 4) {
        const float* kr = Km + (size_t)cols[e] * E;
        float acc = 0.f;
        #pragma unroll
        for (int i = 0; i < 2; ++i) {
            const float4 kv = *(const float4*)(kr + i * 256 + lane * 4);
            const float4 qv = *(const float4*)(&qrow[i * 256 + lane * 4]);
            acc += kv.x * qv.x + kv.y * qv.y + kv.z * qv.z + kv.w * qv.w;
        }
        acc = waveSum(acc);
        if (lane == 0) sc[e] = acc * scale;
    }
    __syncthreads();

    float lm = -3.4e38f;
    for (int e = t; e < nE; e += 256) lm = fmaxf(lm, sc[e]);
    lm = waveMax(lm);
    if (lane == 0) red[wave] = lm;
    __syncthreads();
    const float m = fmaxf(fmaxf(red[0], red[1]), fmaxf(red[2], red[3]));
    __syncthreads();

    float ls = 0.f;
    for (int e = t; e < nE; e += 256) ls += expf(sc[e] - m);
    ls = waveSum(ls);
    if (lane == 0) red[wave] = ls;
    __syncthreads();
    const float inv = 1.0f / (red[0] + red[1] + red[2] + red[3]);
    __syncthreads();

    float ent = 0.f;
    for (int e = t; e < nE; e += 256) {
        const float p = expf(sc[e] - m) * inv;
        attn[rowbase + cols[e]] = p;
        ent -= p * logf(p + 1e-10f);
    }
    ent = waveSum(ent);
    if (lane == 0) red[wave] = ent;
    __syncthreads();
    if (t == 0) atomicAdd(entAcc, red[0] + red[1] + red[2] + red[3]);
}

__global__ __launch_bounds__(256)
void phase_k(const float* __restrict__ Q, const float* __restrict__ K,
             float* __restrict__ out)
{
    const size_t i = (size_t)blockIdx.x * 256 + threadIdx.x;
    out[i] = atan2f(K[i], Q[i]);
}

__global__ void coh_k(const float* __restrict__ ent, float* __restrict__ out)
{
    out[0] = 1.0f - ent[0] / logf(4096.0f);
}

// ---------------------------------------------------------------------------
extern "C" void kernel_launch(void* const* d_in, const int* in_sizes, int n_in,
                              void* d_out, int out_size, void* d_ws, size_t ws_size,
                              hipStream_t stream)
{
    const float* x    = (const float*)d_in[0];
    const int*   ei   = (const int*)  d_in[1];
    const int*   ct   = (const int*)  d_in[2];
    const float* Wq   = (const float*)d_in[3];
    const float* bq   = (const float*)d_in[4];
    const float* Wk   = (const float*)d_in[5];
    const float* bk   = (const float*)d_in[6];
    const float* Wv   = (const float*)d_in[7];
    const float* bv   = (const float*)d_in[8];
    const float* bio  = (const float*)d_in[9];
    const float* cemb = (const float*)d_in[10];
    const float* ipw  = (const float*)d_in[11];
    const float* ipb  = (const float*)d_in[12];
    const float* ow   = (const float*)d_in[13];
    const float* ob   = (const float*)d_in[14];

    const size_t NE = (size_t)N_NODES * E;   // 2,097,152

    // ws: survives until edge_attn/phase
    float* Qf = (float*)d_ws;                 // [4096][512] fp32
    float* Kf = Qf + NE;
    unsigned* mask = (unsigned*)(Kf + NE);    // 2 MB (+4B entAcc right after)
    float* entAcc = (float*)(mask + (size_t)N_NODES * (N_NODES / 32));

    // outputs
    float* outAttended = (float*)d_out;                    // [4096,512]
    float* outAttn  = outAttended + NE;                    // [4096,4096]
    float* outPhase = outAttn + (size_t)N_NODES * N_NODES; // [4096,512]
    float* outCoh   = outPhase + NE;                       // scalar

    // scratch carved from the attn output region (dead until edge_attn)
    float* Opart = outAttn;                                  // 4,194,304 f
    float* Mpart = outAttn + 4194304;                        // 65,536 f
    float* Lpart = outAttn + 4259840;                        // 65,536 f
    short* obf   = (short*)(outAttn + 4325376);              // 2M shorts
    short* vt    = (short*)(outAttn + 5373952);              // [H][HD][N]
    short* qh    = (short*)(outAttn + 6422528);              // [H][N][HD]
    short* kh    = (short*)(outAttn + 7471104);
    short* Qbf   = (short*)(outAttn + 8519680);              // [N][E]
    short* Kbf   = (short*)(outAttn + 9568256);
    short* xhi   = (short*)(outAttn + 10616832);             // [N][DIN]
    short* xlo   = (short*)(outAttn + 11141120);
    short* Wthi  = (short*)(outAttn + 11665408);             // [1536][256]
    short* Wtlo  = (short*)(outAttn + 11862016);
    short* ipwbf = (short*)(outAttn + 12058624);             // [1024][512]
    short* owbf  = (short*)(outAttn + 12320768);             // [512][512]
    float* beff  = outAttn + 12713984;                       // [1536]

    const dim3 blk(256);

    // mask + entAcc in one memset (entAcc is adjacent)
    (void)hipMemsetAsync(mask, 0, (size_t)N_NODES * (N_NODES / 32) * sizeof(unsigned) + 4, stream);
    mask_build_k<<<dim3(NEDGE / 256), blk, 0, stream>>>(ei, mask);

    // effective weights (bio^T staged on the fly for z=0) + all conversions
    prep_gemm_k<<<dim3(4, 8, 3), blk, 0, stream>>>(bio, ipw, Wq, Wk, Wv, Wthi, Wtlo);
    conv_all_k<<<dim3(1798), blk, 0, stream>>>(x, ipw, ow, bq, bk, bv, bio, ipb,
                                               xhi, xlo, ipwbf, owbf, beff);

    // main fused GEMM: [Q|K|v] = x @ Weff^T (+ ce, beff); v -> vt bf16 direct
    mf_gemm_k<true, 0><<<dim3(12, 32, 1), blk, 0, stream>>>(
        xhi, xlo, Wthi, Wtlo, DIN, beff, cemb, ct,
        Qf, Kf, Qbf, Kbf, vt);

    // in_proj q/k -> bf16 head-major
    mf_gemm_k<false, 1><<<dim3(4, 32, 2), blk, 0, stream>>>(
        Qbf, Kbf, ipwbf, nullptr, E, ipb, nullptr, nullptr,
        nullptr, nullptr, qh, kh, nullptr);

    // flash MHA (key-split 2, double-buffered) + combine
    flash_mha_k<<<dim3(N_NODES / 64, NH, 2), blk, 0, stream>>>(qh, kh, vt, Opart, Mpart, Lpart);
    combine_k<<<dim3((unsigned)(NE / 4 / 256)), blk, 0, stream>>>(Opart, Mpart, Lpart, obf);

    // attended = o @ out_w^T + out_b
    mf_gemm_k<false, 2><<<dim3(4, 32, 1), blk, 0, stream>>>(
        obf, nullptr, owbf, nullptr, E, ob, nullptr, nullptr,
        outAttended, nullptr, nullptr, nullptr, nullptr);

    // phase
    phase_k<<<dim3((unsigned)(NE / 256)), blk, 0, stream>>>(Qf, Kf, outPhase);

    // edge-sparse graph attention + entropy (overwrites attn-region scratch)
    edge_attn_k<<<dim3(N_NODES), blk, 0, stream>>>(Qf, Kf, mask, outAttn, entAcc);

    coh_k<<<1, 1, 0, stream>>>(entAcc, outCoh);
}

// Round 9
// 350.137 us; speedup vs baseline: 4.9236x; 1.1271x over previous
//
#include <hip/hip_runtime.h>
#include <hip/hip_bf16.h>
#include <math.h>

#define N_NODES 4096
#define DIN     256
#define E       512
#define NH      8
#define HD      64
#define NEDGE   131072
#define MAXE    1024
#define LSC     0.180336880111120f   // 0.125 * log2(e)
#define KSPLIT  4

typedef short bf16x8 __attribute__((ext_vector_type(8)));
typedef float f32x4  __attribute__((ext_vector_type(4)));

__device__ inline short f2bf(float f) {
    __hip_bfloat16 h = __float2bfloat16(f);   // RNE
    return __builtin_bit_cast(short, h);
}
__device__ inline float bfbits2f(short s) {
    return __bfloat162float(__builtin_bit_cast(__hip_bfloat16, s));
}
__device__ inline void dec2(float f, short& h, short& l) {
    h = f2bf(f);
    l = f2bf(f - bfbits2f(h));
}
__device__ inline unsigned packbf2(float a, float b) {
    return (unsigned)(unsigned short)f2bf(a) |
           ((unsigned)(unsigned short)f2bf(b) << 16);
}

// ---------------------------------------------------------------------------
// fp32 GEMM for effective weights: C[512x256], z: (bio^T@Wq | bio@Wk | wv_i@Wv)
// z=0 stages bio transposed on the fly. Output split-bf16 to Wt[1536][256].
__global__ __launch_bounds__(256)
void prep_gemm_k(const float* __restrict__ bio, const float* __restrict__ ipw,
                 const float* __restrict__ Wq, const float* __restrict__ Wk,
                 const float* __restrict__ Wv,
                 short* __restrict__ Whi, short* __restrict__ Wlo)
{
    const int z = blockIdx.z;
    const float* A = (z == 2) ? (ipw + (size_t)2 * E * E) : bio;
    const float* B = (z == 0) ? Wq : (z == 1) ? Wk : Wv;

    __shared__ float As[16][68];
    __shared__ float Bs[16][68];

    const int t  = threadIdx.x;
    const int m0 = blockIdx.y * 64;
    const int n0 = blockIdx.x * 64;
    const int ty = t >> 4, tx = t & 15;

    float acc[4][4] = {{0.f}};

    for (int kt = 0; kt < E; kt += 16) {
        if (z == 0) {   // As[k][m] = bio[k][m]  (A^T staging)
            const int kk = t >> 4, nq = (t & 15) << 2;
            *(float4*)&As[kk][nq] = *(const float4*)(A + (size_t)(kt + kk) * E + m0 + nq);
        } else {
            const int row = t >> 2, kq = (t & 3) << 2;
            const float4 va = *(const float4*)(A + (size_t)(m0 + row) * E + kt + kq);
            As[kq + 0][row] = va.x; As[kq + 1][row] = va.y;
            As[kq + 2][row] = va.z; As[kq + 3][row] = va.w;
        }
        {
            const int kk = t >> 4, nq = (t & 15) << 2;
            *(float4*)&Bs[kk][nq] = *(const float4*)(B + (size_t)(kt + kk) * DIN + n0 + nq);
        }
        __syncthreads();
        #pragma unroll
        for (int k = 0; k < 16; ++k) {
            const float4 av = *(const float4*)&As[k][ty << 2];
            const float4 bv = *(const float4*)&Bs[k][tx << 2];
            const float a[4] = {av.x, av.y, av.z, av.w};
            const float b[4] = {bv.x, bv.y, bv.z, bv.w};
            #pragma unroll
            for (int i = 0; i < 4; ++i)
                #pragma unroll
                for (int j = 0; j < 4; ++j)
                    acc[i][j] = fmaf(a[i], b[j], acc[i][j]);
        }
        __syncthreads();
    }

    #pragma unroll
    for (int i = 0; i < 4; ++i) {
        const int row = z * E + m0 + (ty << 2) + i;
        const int col = n0 + (tx << 2);
        #pragma unroll
        for (int j = 0; j < 4; ++j) {
            short h, l;
            dec2(acc[i][j], h, l);
            Whi[(size_t)row * DIN + col + j] = h;
            Wlo[(size_t)row * DIN + col + j] = l;
        }
    }
}

// ---------------------------------------------------------------------------
// merged conversions: x split-bf16 | ipw(q,k rows) bf16 | ow bf16 | beff
__global__ __launch_bounds__(256)
void conv_all_k(const float* __restrict__ x, const float* __restrict__ ipw,
                const float* __restrict__ ow,
                const float* __restrict__ bq, const float* __restrict__ bk,
                const float* __restrict__ bv, const float* __restrict__ bio,
                const float* __restrict__ ipb,
                short* __restrict__ xhi, short* __restrict__ xlo,
                short* __restrict__ ipwbf, short* __restrict__ owbf,
                float* __restrict__ beff)
{
    const int b = blockIdx.x, t = threadIdx.x;
    if (b < 1024) {                       // x: 1,048,576 elements, split hi/lo
        const size_t i = ((size_t)b * 256 + t) * 4;
        const float4 v = *(const float4*)(x + i);
        short4 h, l;
        dec2(v.x, h.x, l.x); dec2(v.y, h.y, l.y);
        dec2(v.z, h.z, l.z); dec2(v.w, h.w, l.w);
        *(short4*)(xhi + i) = h;
        *(short4*)(xlo + i) = l;
    } else if (b < 1536) {                // ipw rows 0..1024: 524,288 elements
        const size_t i = ((size_t)(b - 1024) * 256 + t) * 4;
        const float4 v = *(const float4*)(ipw + i);
        short4 o; o.x = f2bf(v.x); o.y = f2bf(v.y); o.z = f2bf(v.z); o.w = f2bf(v.w);
        *(short4*)(ipwbf + i) = o;
    } else if (b < 1792) {                // ow: 262,144 elements
        const size_t i = ((size_t)(b - 1536) * 256 + t) * 4;
        const float4 v = *(const float4*)(ow + i);
        short4 o; o.x = f2bf(v.x); o.y = f2bf(v.y); o.z = f2bf(v.z); o.w = f2bf(v.w);
        *(short4*)(owbf + i) = o;
    } else {                              // effective biases: 1536 values
        const int n = (b - 1792) * 256 + t;
        float s = 0.f;
        if (n < 512) {
            for (int e = 0; e < E; ++e) s += bq[e] * bio[(size_t)e * E + n];
        } else if (n < 1024) {
            const int nn = n - 512;
            for (int e = 0; e < E; ++e) s += bk[e] * bio[(size_t)nn * E + e];
        } else {
            const int nn = n - 1024;
            const float* wvi = ipw + (size_t)2 * E * E + (size_t)nn * E;
            for (int e = 0; e < E; ++e) s += bv[e] * wvi[e];
            s += ipb[1024 + nn];
        }
        beff[n] = s;
    }
}

// ---------------------------------------------------------------------------
// bf16 MFMA GEMM, NT: C[M][N] = A[M][K] @ B[N][K]^T. 128x128, BK=64, swizzled.
// EPI 0 (MAIN): +beff; cols<1024: +0.1*ce -> Qf/Kf fp32 + Qbf/Kbf bf16;
//               cols>=1024: v -> bf16 transposed [H][HD][N] (vt).
// EPI 1 (HEAD): z-select; +bias; bf16 head-major [H][N][HD].
// EPI 2 (OUT):  +bias; fp32.
template<bool SPLIT, int EPI>
__global__ __launch_bounds__(256)
void mf_gemm_k(const short* __restrict__ Ah, const short* __restrict__ Al,
               const short* __restrict__ Bh, const short* __restrict__ Bl,
               int K,
               const float* __restrict__ beff, const float* __restrict__ cemb,
               const int* __restrict__ ctype,
               float* __restrict__ f32a, float* __restrict__ f32b,
               short* __restrict__ b16a, short* __restrict__ b16b,
               short* __restrict__ b16c)
{
    constexpr int NSL = SPLIT ? 2 : 1;
    __shared__ __align__(16) short As[NSL][128 * 64];
    __shared__ __align__(16) short Bs[NSL][128 * 64];

    const int t = threadIdx.x;
    const int w = t >> 6, lane = t & 63;
    const int quad = lane >> 4, l16 = lane & 15;
    const int m0 = blockIdx.y * 128, n0 = blockIdx.x * 128;
    const int mw = (w >> 1) * 64, nw = (w & 1) * 64;

    const short* Ause = Ah;
    const short* Buse = Bh;
    const float* biasu = beff;
    short* dstu = b16a;
    if (EPI == 1 && blockIdx.z == 1) {
        Ause = Al; Buse = Bh + (size_t)E * E; biasu = beff + E; dstu = b16b;
    }

    f32x4 acc[4][4];
    #pragma unroll
    for (int i = 0; i < 4; ++i)
        #pragma unroll
        for (int j = 0; j < 4; ++j) acc[i][j] = (f32x4){0.f, 0.f, 0.f, 0.f};

    for (int kt = 0; kt < K; kt += 64) {
        __syncthreads();
        #pragma unroll
        for (int it = 0; it < 4; ++it) {
            const int idx = it * 256 + t;
            const int row = idx >> 3, ch = idx & 7;
            const int lo = row * 64 + ((ch ^ (row & 7)) << 3);
            *(bf16x8*)&As[0][lo] = *(const bf16x8*)(Ause + (size_t)(m0 + row) * K + kt + ch * 8);
            *(bf16x8*)&Bs[0][lo] = *(const bf16x8*)(Buse + (size_t)(n0 + row) * K + kt + ch * 8);
            if (SPLIT) {
                *(bf16x8*)&As[1][lo] = *(const bf16x8*)(Al + (size_t)(m0 + row) * K + kt + ch * 8);
                *(bf16x8*)&Bs[1][lo] = *(const bf16x8*)(Bl + (size_t)(n0 + row) * K + kt + ch * 8);
            }
        }
        __syncthreads();

        #pragma unroll
        for (int kk = 0; kk < 2; ++kk) {
            bf16x8 af[4], bf_[4], afl[4], bfl[4];
            #pragma unroll
            for (int i = 0; i < 4; ++i) {
                const int lo = (mw + 16 * i + l16) * 64 + (((kk * 4 + quad) ^ (l16 & 7)) << 3);
                af[i] = *(const bf16x8*)&As[0][lo];
                if (SPLIT) afl[i] = *(const bf16x8*)&As[1][lo];
            }
            #pragma unroll
            for (int j = 0; j < 4; ++j) {
                const int lo = (nw + 16 * j + l16) * 64 + (((kk * 4 + quad) ^ (l16 & 7)) << 3);
                bf_[j] = *(const bf16x8*)&Bs[0][lo];
                if (SPLIT) bfl[j] = *(const bf16x8*)&Bs[1][lo];
            }
            #pragma unroll
            for (int i = 0; i < 4; ++i)
                #pragma unroll
                for (int j = 0; j < 4; ++j) {
                    acc[i][j] = __builtin_amdgcn_mfma_f32_16x16x32_bf16(af[i], bf_[j], acc[i][j], 0, 0, 0);
                    if (SPLIT) {
                        acc[i][j] = __builtin_amdgcn_mfma_f32_16x16x32_bf16(af[i], bfl[j], acc[i][j], 0, 0, 0);
                        acc[i][j] = __builtin_amdgcn_mfma_f32_16x16x32_bf16(afl[i], bf_[j], acc[i][j], 0, 0, 0);
                    }
                }
        }
    }

    #pragma unroll
    for (int i = 0; i < 4; ++i) {
        const int row0 = m0 + mw + 16 * i + quad * 4;
        #pragma unroll
        for (int j = 0; j < 4; ++j) {
            const int col = n0 + nw + 16 * j + l16;
            if (EPI == 0 && col >= 1024) {   // v -> vt bf16 [H][HD][N], 4 rows packed
                const int hh = (col - 1024) >> 6, d = (col - 1024) & 63;
                short4 o;
                o.x = f2bf(acc[i][j][0] + beff[col]);
                o.y = f2bf(acc[i][j][1] + beff[col]);
                o.z = f2bf(acc[i][j][2] + beff[col]);
                o.w = f2bf(acc[i][j][3] + beff[col]);
                *(short4*)(b16c + ((size_t)hh * HD + d) * N_NODES + row0) = o;
                continue;
            }
            #pragma unroll
            for (int r = 0; r < 4; ++r) {
                const int row = row0 + r;
                float v = acc[i][j][r];
                if (EPI == 0) {
                    v += beff[col];
                    const int cc = col & 511;
                    v += 0.1f * cemb[(size_t)ctype[row] * E + cc];
                    if (col < 512) {
                        f32a[(size_t)row * E + cc] = v;
                        b16a[(size_t)row * E + cc] = f2bf(v);
                    } else {
                        f32b[(size_t)row * E + cc] = v;
                        b16b[(size_t)row * E + cc] = f2bf(v);
                    }
                } else if (EPI == 1) {
                    v += biasu[col];
                    dstu[((size_t)(col >> 6) * N_NODES + row) * HD + (col & 63)] = f2bf(v);
                } else {
                    v += biasu[col];
                    f32a[(size_t)row * E + col] = v;
                }
            }
        }
    }
}

// ---------------------------------------------------------------------------
// flash MHA, S^T formulation, key-split KSPLIT, fixed-max exp2 softmax
// (scores bounded: |S|*LSC << 127, no overflow; softmax is shift-invariant).
// qh,kh: [H][N][HD] bf16 ; vt: [H][HD][N] bf16
// Opart: [KSPLIT][H][N][HD] fp32 (unnormalized) ; Lpart: [KSPLIT][H][N]
__global__ __launch_bounds__(256)
void flash_mha_k(const short* __restrict__ qh, const short* __restrict__ kh,
                 const short* __restrict__ vt, float* __restrict__ Opart,
                 float* __restrict__ Lpart)
{
    const int h = blockIdx.y, z = blockIdx.z;
    const int q0 = blockIdx.x * 64;
    const int t = threadIdx.x, wave = t >> 6, lane = t & 63;
    const int quad = lane >> 4, l16 = lane & 15;
    const int sw = l16 & 7;

    __shared__ __align__(16) short Kt[64 * 64];
    __shared__ __align__(16) short Vs[64 * 64];
    __shared__ __align__(16) short Pt[4][16 * 64];

    const short* qb = qh + ((size_t)h * N_NODES + q0 + wave * 16 + l16) * HD;
    const bf16x8 aq0 = *(const bf16x8*)(qb + quad * 8);
    const bf16x8 aq1 = *(const bf16x8*)(qb + 32 + quad * 8);

    f32x4 O[4];
    #pragma unroll
    for (int c = 0; c < 4; ++c) O[c] = (f32x4){0.f, 0.f, 0.f, 0.f};
    float lr = 0.f;

    const short* kb = kh + (size_t)h * N_NODES * HD;
    const short* vb = vt + (size_t)h * HD * N_NODES;
    const int c0 = (quad ^ sw) << 3;
    const int c1 = c0 ^ 32;

    const int r_ = t >> 3, ch_ = (t & 7);
    const int lo0 = r_ * 64 + ((ch_ ^ (r_ & 7)) << 3);
    const int r1_ = r_ + 32;
    const int lo1 = r1_ * 64 + ((ch_ ^ (r1_ & 7)) << 3);

    const int kbeg = z * (N_NODES / KSPLIT);
    for (int k0 = kbeg; k0 < kbeg + N_NODES / KSPLIT; k0 += 64) {
        __syncthreads();
        *(bf16x8*)&Kt[lo0] = *(const bf16x8*)(kb + (size_t)(k0 + r_) * HD + ch_ * 8);
        *(bf16x8*)&Vs[lo0] = *(const bf16x8*)(vb + (size_t)r_ * N_NODES + k0 + ch_ * 8);
        *(bf16x8*)&Kt[lo1] = *(const bf16x8*)(kb + (size_t)(k0 + r1_) * HD + ch_ * 8);
        *(bf16x8*)&Vs[lo1] = *(const bf16x8*)(vb + (size_t)r1_ * N_NODES + k0 + ch_ * 8);
        __syncthreads();

        // S^T = K Q^T : rows = keys, cols = queries (this lane: query l16)
        f32x4 S[4];
        #pragma unroll
        for (int c = 0; c < 4; ++c) {
            const int rb = (16 * c + l16) * 64;
            const bf16x8 kf0 = *(const bf16x8*)&Kt[rb + c0];
            const bf16x8 kf1 = *(const bf16x8*)&Kt[rb + c1];
            f32x4 a = {0.f, 0.f, 0.f, 0.f};
            a = __builtin_amdgcn_mfma_f32_16x16x32_bf16(kf0, aq0, a, 0, 0, 0);
            a = __builtin_amdgcn_mfma_f32_16x16x32_bf16(kf1, aq1, a, 0, 0, 0);
            S[c] = a;
        }

        // fixed-max softmax: p = 2^(S*LSC), accumulate l in-lane
        #pragma unroll
        for (int c = 0; c < 4; ++c)
            #pragma unroll
            for (int r = 0; r < 4; ++r) {
                const float p = exp2f(S[c][r] * LSC);
                S[c][r] = p;
                lr += p;
            }

        // P[query][key] -> LDS (packed b32), read back as A-fragments
        #pragma unroll
        for (int c = 0; c < 4; ++c) {
            const int chunk = 2 * c + (quad >> 1);
            const int off = l16 * 64 + ((chunk ^ sw) << 3) + (quad & 1) * 4;
            *(unsigned*)&Pt[wave][off]     = packbf2(S[c][0], S[c][1]);
            *(unsigned*)&Pt[wave][off + 2] = packbf2(S[c][2], S[c][3]);
        }
        const bf16x8 pf0 = *(const bf16x8*)&Pt[wave][l16 * 64 + c0];
        const bf16x8 pf1 = *(const bf16x8*)&Pt[wave][l16 * 64 + c1];
        #pragma unroll
        for (int c = 0; c < 4; ++c) {
            const int rb = (16 * c + l16) * 64;
            const bf16x8 vf0 = *(const bf16x8*)&Vs[rb + c0];
            const bf16x8 vf1 = *(const bf16x8*)&Vs[rb + c1];
            O[c] = __builtin_amdgcn_mfma_f32_16x16x32_bf16(pf0, vf0, O[c], 0, 0, 0);
            O[c] = __builtin_amdgcn_mfma_f32_16x16x32_bf16(pf1, vf1, O[c], 0, 0, 0);
        }
    }

    // reduce l across the 4 quads holding the same query l16
    lr += __shfl_xor(lr, 16);
    lr += __shfl_xor(lr, 32);

    const size_t zb = ((size_t)z * NH + h) * N_NODES;
    #pragma unroll
    for (int c = 0; c < 4; ++c)
        #pragma unroll
        for (int r = 0; r < 4; ++r)
            Opart[(zb + q0 + wave * 16 + quad * 4 + r) * HD + 16 * c + l16] = O[c][r];
    if (quad == 0)
        Lpart[zb + q0 + wave * 16 + l16] = lr;
}

// combine the KSPLIT halves -> o (bf16 [N][E]); shift-invariant (no max needed)
__global__ __launch_bounds__(256)
void combine_k(const float* __restrict__ Opart, const float* __restrict__ Lp,
               short* __restrict__ obf)
{
    const int idx = blockIdx.x * 256 + threadIdx.x;
    const int e4 = idx * 4;
    const int q = e4 >> 9;
    const int col = e4 & 511;
    const int h = col >> 6, d = col & 63;
    float4 s = {0.f, 0.f, 0.f, 0.f};
    float l = 0.f;
    #pragma unroll
    for (int z = 0; z < KSPLIT; ++z) {
        const size_t b = ((size_t)z * NH + h) * N_NODES + q;
        const float4 o = *(const float4*)&Opart[b * HD + d];
        s.x += o.x; s.y += o.y; s.z += o.z; s.w += o.w;
        l += Lp[b];
    }
    const float inv = 1.0f / l;
    short4 o;
    o.x = f2bf(s.x * inv); o.y = f2bf(s.y * inv);
    o.z = f2bf(s.z * inv); o.w = f2bf(s.w * inv);
    *(short4*)&obf[(size_t)q * E + col] = o;
}

// ---------------------------------------------------------------------------
__global__ __launch_bounds__(256)
void mask_build_k(const int* __restrict__ ei, unsigned* __restrict__ mask)
{
    const int i = blockIdx.x * 256 + threadIdx.x;
    const int r = ei[i];
    const int c = ei[NEDGE + i];
    atomicOr(&mask[(size_t)r * (N_NODES / 32) + (c >> 5)], 1u << (c & 31));
}

__device__ inline float waveMax(float v) {
    #pragma unroll
    for (int o = 32; o; o >>= 1) v = fmaxf(v, __shfl_xor(v, o));
    return v;
}
__device__ inline float waveSum(float v) {
    #pragma unroll
    for (int o = 32; o; o >>= 1) v += __shfl_xor(v, o);
    return v;
}

// One block per row (round-5 validated form): zero the row, enumerate edge
// columns from the bitmask, fp32 dot(Q[row], K[col]) one edge per wave, exact
// softmax over edges, scatter p, per-row entropy via PLAIN STORE to entRow
// (no atomics anywhere in the entropy path).
__global__ __launch_bounds__(256)
void edge_attn_k(const float* __restrict__ Q, const float* __restrict__ Km,
                 const unsigned* __restrict__ mask, float* __restrict__ attn,
                 float* __restrict__ entRow)
{
    const int row = blockIdx.x;
    const int t = threadIdx.x;
    const int wave = t >> 6, lane = t & 63;
    const size_t rowbase = (size_t)row * N_NODES;

    __shared__ float qrow[E];
    __shared__ int cols[MAXE];
    __shared__ float sc[MAXE];
    __shared__ int cnt;
    __shared__ float red[4];

    {
        const float4 zv = {0.f, 0.f, 0.f, 0.f};
        #pragma unroll
        for (int j = 0; j < 4; ++j)
            *(float4*)&attn[rowbase + j * 1024 + t * 4] = zv;
    }
    qrow[t] = Q[(size_t)row * E + t];
    qrow[256 + t] = Q[(size_t)row * E + 256 + t];
    if (t == 0) cnt = 0;
    __syncthreads();

    if (t < 128) {
        unsigned wm = mask[(size_t)row * (N_NODES / 32) + t];
        while (wm) {
            const int b = __ffs(wm) - 1;
            wm &= wm - 1;
            const int idx = atomicAdd(&cnt, 1);
            cols[idx] = t * 32 + b;
        }
    }
    __syncthreads();
    const int nE = cnt;

    if (nE == 0) {   // uniform row (unreachable for this input, but exact)
        const float p = 1.0f / 4096.0f;
        for (int j = t; j < N_NODES; j += 256) attn[rowbase + j] = p;
        if (t == 0) entRow[row] = -4096.f * p * logf(p + 1e-10f);
        return;
    }

    const float scale = 0.044194173824159216f;   // 1/sqrt(512)
    for (int e = wave; e < nE; e += 4) {
        const float* kr = Km + (size_t)cols[e] * E;
        float acc = 0.f;
        #pragma unroll
        for (int i = 0; i < 2; ++i) {
            const float4 kv = *(const float4*)(kr + i * 256 + lane * 4);
            const float4 qv = *(const float4*)(&qrow[i * 256 + lane * 4]);
            acc += kv.x * qv.x + kv.y * qv.y + kv.z * qv.z + kv.w * qv.w;
        }
        acc = waveSum(acc);
        if (lane == 0) sc[e] = acc * scale;
    }
    __syncthreads();

    float lm = -3.4e38f;
    for (int e = t; e < nE; e += 256) lm = fmaxf(lm, sc[e]);
    lm = waveMax(lm);
    if (lane == 0) red[wave] = lm;
    __syncthreads();
    const float m = fmaxf(fmaxf(red[0], red[1]), fmaxf(red[2], red[3]));
    __syncthreads();

    float ls = 0.f;
    for (int e = t; e < nE; e += 256) ls += expf(sc[e] - m);
    ls = waveSum(ls);
    if (lane == 0) red[wave] = ls;
    __syncthreads();
    const float inv = 1.0f / (red[0] + red[1] + red[2] + red[3]);
    __syncthreads();   // red[] reused below

    float ent = 0.f;
    for (int e = t; e < nE; e += 256) {
        const float p = expf(sc[e] - m) * inv;
        attn[rowbase + cols[e]] = p;
        ent -= p * logf(p + 1e-10f);
    }
    ent = waveSum(ent);
    if (lane == 0) red[wave] = ent;
    __syncthreads();
    if (t == 0) entRow[row] = red[0] + red[1] + red[2] + red[3];
}

// deterministic single-block reduction of entRow -> coherence
__global__ __launch_bounds__(256)
void coh_k(const float* __restrict__ entRow, float* __restrict__ out)
{
    __shared__ float red[4];
    const int t = threadIdx.x;
    float s = 0.f;
    for (int i = t; i < N_NODES; i += 256) s += entRow[i];
    s = waveSum(s);
    if ((t & 63) == 0) red[t >> 6] = s;
    __syncthreads();
    if (t == 0)
        out[0] = 1.0f - (red[0] + red[1] + red[2] + red[3]) / logf(4096.0f);
}

__global__ __launch_bounds__(256)
void phase_k(const float* __restrict__ Q, const float* __restrict__ K,
             float* __restrict__ out)
{
    const size_t i = (size_t)blockIdx.x * 256 + threadIdx.x;
    out[i] = atan2f(K[i], Q[i]);
}

// ---------------------------------------------------------------------------
extern "C" void kernel_launch(void* const* d_in, const int* in_sizes, int n_in,
                              void* d_out, int out_size, void* d_ws, size_t ws_size,
                              hipStream_t stream)
{
    const float* x    = (const float*)d_in[0];
    const int*   ei   = (const int*)  d_in[1];
    const int*   ct   = (const int*)  d_in[2];
    const float* Wq   = (const float*)d_in[3];
    const float* bq   = (const float*)d_in[4];
    const float* Wk   = (const float*)d_in[5];
    const float* bk   = (const float*)d_in[6];
    const float* Wv   = (const float*)d_in[7];
    const float* bv   = (const float*)d_in[8];
    const float* bio  = (const float*)d_in[9];
    const float* cemb = (const float*)d_in[10];
    const float* ipw  = (const float*)d_in[11];
    const float* ipb  = (const float*)d_in[12];
    const float* ow   = (const float*)d_in[13];
    const float* ob   = (const float*)d_in[14];

    const size_t NE = (size_t)N_NODES * E;   // 2,097,152

    // ws: survives until edge_attn/phase
    float* Qf = (float*)d_ws;                 // [4096][512] fp32
    float* Kf = Qf + NE;
    unsigned* mask = (unsigned*)(Kf + NE);    // 2 MB
    float* entRow = (float*)(mask + (size_t)N_NODES * (N_NODES / 32));  // [4096]

    // outputs
    float* outAttended = (float*)d_out;                    // [4096,512]
    float* outAttn  = outAttended + NE;                    // [4096,4096]
    float* outPhase = outAttn + (size_t)N_NODES * N_NODES; // [4096,512]
    float* outCoh   = outPhase + NE;                       // scalar

    // scratch carved from the attn output region (dead until edge_attn).
    // Float-slot offsets, sizes verified (bf16 buffers = elements/2 slots):
    //   Opart  [4][8][4096][64] f32        0 ..  8,388,608
    //   Lpart  [4][8][4096] f32     8,388,608 ..  8,519,680
    //   obf    [4096][512] bf16     8,519,680 ..  9,568,256
    //   vt     [8][64][4096] bf16   9,568,256 .. 10,616,832
    //   qh     [8][4096][64] bf16  10,616,832 .. 11,665,408
    //   kh     [8][4096][64] bf16  11,665,408 .. 12,713,984
    //   Qbf    [4096][512] bf16    12,713,984 .. 13,762,560
    //   Kbf    [4096][512] bf16    13,762,560 .. 14,811,136
    //   xhi    [4096][256] bf16    14,811,136 .. 15,335,424   (524,288 slots!)
    //   xlo    [4096][256] bf16    15,335,424 .. 15,859,712
    //   Wthi   [1536][256] bf16    15,859,712 .. 16,056,320
    //   Wtlo   [1536][256] bf16    16,056,320 .. 16,252,928
    //   ipwbf  [1024][512] bf16    16,252,928 .. 16,515,072
    //   owbf   [512][512] bf16     16,515,072 .. 16,646,144
    //   beff   [1536] f32          16,646,144 .. 16,647,680  (< 16,777,216 ✓)
    float* Opart = outAttn;
    float* Lpart = outAttn + 8388608;
    short* obf   = (short*)(outAttn + 8519680);
    short* vt    = (short*)(outAttn + 9568256);
    short* qh    = (short*)(outAttn + 10616832);
    short* kh    = (short*)(outAttn + 11665408);
    short* Qbf   = (short*)(outAttn + 12713984);
    short* Kbf   = (short*)(outAttn + 13762560);
    short* xhi   = (short*)(outAttn + 14811136);
    short* xlo   = (short*)(outAttn + 15335424);
    short* Wthi  = (short*)(outAttn + 15859712);
    short* Wtlo  = (short*)(outAttn + 16056320);
    short* ipwbf = (short*)(outAttn + 16252928);
    short* owbf  = (short*)(outAttn + 16515072);
    float* beff  = outAttn + 16646144;

    const dim3 blk(256);

    (void)hipMemsetAsync(mask, 0, (size_t)N_NODES * (N_NODES / 32) * sizeof(unsigned), stream);
    mask_build_k<<<dim3(NEDGE / 256), blk, 0, stream>>>(ei, mask);

    // effective weights (bio^T staged on the fly for z=0) + all conversions
    prep_gemm_k<<<dim3(4, 8, 3), blk, 0, stream>>>(bio, ipw, Wq, Wk, Wv, Wthi, Wtlo);
    conv_all_k<<<dim3(1798), blk, 0, stream>>>(x, ipw, ow, bq, bk, bv, bio, ipb,
                                               xhi, xlo, ipwbf, owbf, beff);

    // main fused GEMM: [Q|K|v] = x @ Weff^T (+ ce, beff); v -> vt bf16 direct
    mf_gemm_k<true, 0><<<dim3(12, 32, 1), blk, 0, stream>>>(
        xhi, xlo, Wthi, Wtlo, DIN, beff, cemb, ct,
        Qf, Kf, Qbf, Kbf, vt);

    // in_proj q/k -> bf16 head-major
    mf_gemm_k<false, 1><<<dim3(4, 32, 2), blk, 0, stream>>>(
        Qbf, Kbf, ipwbf, nullptr, E, ipb, nullptr, nullptr,
        nullptr, nullptr, qh, kh, nullptr);

    // flash MHA (key-split 4, fixed-max) + combine
    flash_mha_k<<<dim3(N_NODES / 64, NH, KSPLIT), blk, 0, stream>>>(qh, kh, vt, Opart, Lpart);
    combine_k<<<dim3((unsigned)(NE / 4 / 256)), blk, 0, stream>>>(Opart, Lpart, obf);

    // attended = o @ out_w^T + out_b
    mf_gemm_k<false, 2><<<dim3(4, 32, 1), blk, 0, stream>>>(
        obf, nullptr, owbf, nullptr, E, ob, nullptr, nullptr,
        outAttended, nullptr, nullptr, nullptr, nullptr);

    // phase
    phase_k<<<dim3((unsigned)(NE / 256)), blk, 0, stream>>>(Qf, Kf, outPhase);

    // edge-sparse graph attention + per-row entropy (plain stores)
    edge_attn_k<<<dim3(N_NODES), blk, 0, stream>>>(Qf, Kf, mask, outAttn, entRow);

    // deterministic entropy reduction -> coherence
    coh_k<<<dim3(1), blk, 0, stream>>>(entRow, outCoh);
}

// Round 10
// 341.807 us; speedup vs baseline: 5.0436x; 1.0244x over previous
//
#include <hip/hip_runtime.h>
#include <hip/hip_bf16.h>
#include <math.h>

#define N_NODES 4096
#define DIN     256
#define E       512
#define NH      8
#define HD      64
#define NEDGE   131072
#define MAXE    1024
#define LSC     0.180336880111120f   // 0.125 * log2(e)
#define KSPLIT  4

typedef short bf16x8 __attribute__((ext_vector_type(8)));
typedef float f32x4  __attribute__((ext_vector_type(4)));

__device__ inline short f2bf(float f) {
    __hip_bfloat16 h = __float2bfloat16(f);   // RNE
    return __builtin_bit_cast(short, h);
}
__device__ inline float bfbits2f(short s) {
    return __bfloat162float(__builtin_bit_cast(__hip_bfloat16, s));
}
__device__ inline void dec2(float f, short& h, short& l) {
    h = f2bf(f);
    l = f2bf(f - bfbits2f(h));
}
__device__ inline unsigned packbf2(float a, float b) {
    return (unsigned)(unsigned short)f2bf(a) |
           ((unsigned)(unsigned short)f2bf(b) << 16);
}

// ---------------------------------------------------------------------------
// fp32 GEMM for effective weights: C[512x256], z: (bio^T@Wq | bio@Wk | wv_i@Wv)
// z=0 stages bio transposed on the fly. Output split-bf16 to Wt[1536][256].
__global__ __launch_bounds__(256)
void prep_gemm_k(const float* __restrict__ bio, const float* __restrict__ ipw,
                 const float* __restrict__ Wq, const float* __restrict__ Wk,
                 const float* __restrict__ Wv,
                 short* __restrict__ Whi, short* __restrict__ Wlo)
{
    const int z = blockIdx.z;
    const float* A = (z == 2) ? (ipw + (size_t)2 * E * E) : bio;
    const float* B = (z == 0) ? Wq : (z == 1) ? Wk : Wv;

    __shared__ float As[16][68];
    __shared__ float Bs[16][68];

    const int t  = threadIdx.x;
    const int m0 = blockIdx.y * 64;
    const int n0 = blockIdx.x * 64;
    const int ty = t >> 4, tx = t & 15;

    float acc[4][4] = {{0.f}};

    for (int kt = 0; kt < E; kt += 16) {
        if (z == 0) {   // As[k][m] = bio[k][m]  (A^T staging)
            const int kk = t >> 4, nq = (t & 15) << 2;
            *(float4*)&As[kk][nq] = *(const float4*)(A + (size_t)(kt + kk) * E + m0 + nq);
        } else {
            const int row = t >> 2, kq = (t & 3) << 2;
            const float4 va = *(const float4*)(A + (size_t)(m0 + row) * E + kt + kq);
            As[kq + 0][row] = va.x; As[kq + 1][row] = va.y;
            As[kq + 2][row] = va.z; As[kq + 3][row] = va.w;
        }
        {
            const int kk = t >> 4, nq = (t & 15) << 2;
            *(float4*)&Bs[kk][nq] = *(const float4*)(B + (size_t)(kt + kk) * DIN + n0 + nq);
        }
        __syncthreads();
        #pragma unroll
        for (int k = 0; k < 16; ++k) {
            const float4 av = *(const float4*)&As[k][ty << 2];
            const float4 bv = *(const float4*)&Bs[k][tx << 2];
            const float a[4] = {av.x, av.y, av.z, av.w};
            const float b[4] = {bv.x, bv.y, bv.z, bv.w};
            #pragma unroll
            for (int i = 0; i < 4; ++i)
                #pragma unroll
                for (int j = 0; j < 4; ++j)
                    acc[i][j] = fmaf(a[i], b[j], acc[i][j]);
        }
        __syncthreads();
    }

    #pragma unroll
    for (int i = 0; i < 4; ++i) {
        const int row = z * E + m0 + (ty << 2) + i;
        const int col = n0 + (tx << 2);
        #pragma unroll
        for (int j = 0; j < 4; ++j) {
            short h, l;
            dec2(acc[i][j], h, l);
            Whi[(size_t)row * DIN + col + j] = h;
            Wlo[(size_t)row * DIN + col + j] = l;
        }
    }
}

// ---------------------------------------------------------------------------
// merged conversions: x split-bf16 | ipw(q,k rows) bf16 | ow bf16 | beff
__global__ __launch_bounds__(256)
void conv_all_k(const float* __restrict__ x, const float* __restrict__ ipw,
                const float* __restrict__ ow,
                const float* __restrict__ bq, const float* __restrict__ bk,
                const float* __restrict__ bv, const float* __restrict__ bio,
                const float* __restrict__ ipb,
                short* __restrict__ xhi, short* __restrict__ xlo,
                short* __restrict__ ipwbf, short* __restrict__ owbf,
                float* __restrict__ beff)
{
    const int b = blockIdx.x, t = threadIdx.x;
    if (b < 1024) {                       // x: 1,048,576 elements, split hi/lo
        const size_t i = ((size_t)b * 256 + t) * 4;
        const float4 v = *(const float4*)(x + i);
        short4 h, l;
        dec2(v.x, h.x, l.x); dec2(v.y, h.y, l.y);
        dec2(v.z, h.z, l.z); dec2(v.w, h.w, l.w);
        *(short4*)(xhi + i) = h;
        *(short4*)(xlo + i) = l;
    } else if (b < 1536) {                // ipw rows 0..1024: 524,288 elements
        const size_t i = ((size_t)(b - 1024) * 256 + t) * 4;
        const float4 v = *(const float4*)(ipw + i);
        short4 o; o.x = f2bf(v.x); o.y = f2bf(v.y); o.z = f2bf(v.z); o.w = f2bf(v.w);
        *(short4*)(ipwbf + i) = o;
    } else if (b < 1792) {                // ow: 262,144 elements
        const size_t i = ((size_t)(b - 1536) * 256 + t) * 4;
        const float4 v = *(const float4*)(ow + i);
        short4 o; o.x = f2bf(v.x); o.y = f2bf(v.y); o.z = f2bf(v.z); o.w = f2bf(v.w);
        *(short4*)(owbf + i) = o;
    } else {                              // effective biases: 1536 values
        const int n = (b - 1792) * 256 + t;
        float s = 0.f;
        if (n < 512) {
            for (int e = 0; e < E; ++e) s += bq[e] * bio[(size_t)e * E + n];
        } else if (n < 1024) {
            const int nn = n - 512;
            for (int e = 0; e < E; ++e) s += bk[e] * bio[(size_t)nn * E + e];
        } else {
            const int nn = n - 1024;
            const float* wvi = ipw + (size_t)2 * E * E + (size_t)nn * E;
            for (int e = 0; e < E; ++e) s += bv[e] * wvi[e];
            s += ipb[1024 + nn];
        }
        beff[n] = s;
    }
}

// ---------------------------------------------------------------------------
// bf16 MFMA GEMM, NT: C[M][N] = A[M][K] @ B[N][K]^T. 128x128, BK=64, swizzled.
// EPI 0 (MAIN): +beff; cols<1024: +0.1*ce -> Qf/Kf fp32 + Qbf/Kbf bf16;
//               cols>=1024: v -> bf16 transposed [H][HD][N] (vt).
// EPI 1 (HEAD): z-select; +bias; ×LSC for z=0 (q pre-scale so flash exp2 takes
//               raw MFMA output); bf16 head-major [H][N][HD].
// EPI 2 (OUT):  +bias; fp32.
template<bool SPLIT, int EPI>
__global__ __launch_bounds__(256)
void mf_gemm_k(const short* __restrict__ Ah, const short* __restrict__ Al,
               const short* __restrict__ Bh, const short* __restrict__ Bl,
               int K,
               const float* __restrict__ beff, const float* __restrict__ cemb,
               const int* __restrict__ ctype,
               float* __restrict__ f32a, float* __restrict__ f32b,
               short* __restrict__ b16a, short* __restrict__ b16b,
               short* __restrict__ b16c)
{
    constexpr int NSL = SPLIT ? 2 : 1;
    __shared__ __align__(16) short As[NSL][128 * 64];
    __shared__ __align__(16) short Bs[NSL][128 * 64];

    const int t = threadIdx.x;
    const int w = t >> 6, lane = t & 63;
    const int quad = lane >> 4, l16 = lane & 15;
    const int m0 = blockIdx.y * 128, n0 = blockIdx.x * 128;
    const int mw = (w >> 1) * 64, nw = (w & 1) * 64;

    const short* Ause = Ah;
    const short* Buse = Bh;
    const float* biasu = beff;
    short* dstu = b16a;
    float qsc = 1.0f;
    if (EPI == 1) {
        if (blockIdx.z == 1) {
            Ause = Al; Buse = Bh + (size_t)E * E; biasu = beff + E; dstu = b16b;
        } else {
            qsc = LSC;   // pre-scale q so flash softmax is exp2(raw S)
        }
    }

    f32x4 acc[4][4];
    #pragma unroll
    for (int i = 0; i < 4; ++i)
        #pragma unroll
        for (int j = 0; j < 4; ++j) acc[i][j] = (f32x4){0.f, 0.f, 0.f, 0.f};

    for (int kt = 0; kt < K; kt += 64) {
        __syncthreads();
        #pragma unroll
        for (int it = 0; it < 4; ++it) {
            const int idx = it * 256 + t;
            const int row = idx >> 3, ch = idx & 7;
            const int lo = row * 64 + ((ch ^ (row & 7)) << 3);
            *(bf16x8*)&As[0][lo] = *(const bf16x8*)(Ause + (size_t)(m0 + row) * K + kt + ch * 8);
            *(bf16x8*)&Bs[0][lo] = *(const bf16x8*)(Buse + (size_t)(n0 + row) * K + kt + ch * 8);
            if (SPLIT) {
                *(bf16x8*)&As[1][lo] = *(const bf16x8*)(Al + (size_t)(m0 + row) * K + kt + ch * 8);
                *(bf16x8*)&Bs[1][lo] = *(const bf16x8*)(Bl + (size_t)(n0 + row) * K + kt + ch * 8);
            }
        }
        __syncthreads();

        #pragma unroll
        for (int kk = 0; kk < 2; ++kk) {
            bf16x8 af[4], bf_[4], afl[4], bfl[4];
            #pragma unroll
            for (int i = 0; i < 4; ++i) {
                const int lo = (mw + 16 * i + l16) * 64 + (((kk * 4 + quad) ^ (l16 & 7)) << 3);
                af[i] = *(const bf16x8*)&As[0][lo];
                if (SPLIT) afl[i] = *(const bf16x8*)&As[1][lo];
            }
            #pragma unroll
            for (int j = 0; j < 4; ++j) {
                const int lo = (nw + 16 * j + l16) * 64 + (((kk * 4 + quad) ^ (l16 & 7)) << 3);
                bf_[j] = *(const bf16x8*)&Bs[0][lo];
                if (SPLIT) bfl[j] = *(const bf16x8*)&Bs[1][lo];
            }
            #pragma unroll
            for (int i = 0; i < 4; ++i)
                #pragma unroll
                for (int j = 0; j < 4; ++j) {
                    acc[i][j] = __builtin_amdgcn_mfma_f32_16x16x32_bf16(af[i], bf_[j], acc[i][j], 0, 0, 0);
                    if (SPLIT) {
                        acc[i][j] = __builtin_amdgcn_mfma_f32_16x16x32_bf16(af[i], bfl[j], acc[i][j], 0, 0, 0);
                        acc[i][j] = __builtin_amdgcn_mfma_f32_16x16x32_bf16(afl[i], bf_[j], acc[i][j], 0, 0, 0);
                    }
                }
        }
    }

    #pragma unroll
    for (int i = 0; i < 4; ++i) {
        const int row0 = m0 + mw + 16 * i + quad * 4;
        #pragma unroll
        for (int j = 0; j < 4; ++j) {
            const int col = n0 + nw + 16 * j + l16;
            if (EPI == 0 && col >= 1024) {   // v -> vt bf16 [H][HD][N], 4 rows packed
                const int hh = (col - 1024) >> 6, d = (col - 1024) & 63;
                short4 o;
                o.x = f2bf(acc[i][j][0] + beff[col]);
                o.y = f2bf(acc[i][j][1] + beff[col]);
                o.z = f2bf(acc[i][j][2] + beff[col]);
                o.w = f2bf(acc[i][j][3] + beff[col]);
                *(short4*)(b16c + ((size_t)hh * HD + d) * N_NODES + row0) = o;
                continue;
            }
            #pragma unroll
            for (int r = 0; r < 4; ++r) {
                const int row = row0 + r;
                float v = acc[i][j][r];
                if (EPI == 0) {
                    v += beff[col];
                    const int cc = col & 511;
                    v += 0.1f * cemb[(size_t)ctype[row] * E + cc];
                    if (col < 512) {
                        f32a[(size_t)row * E + cc] = v;
                        b16a[(size_t)row * E + cc] = f2bf(v);
                    } else {
                        f32b[(size_t)row * E + cc] = v;
                        b16b[(size_t)row * E + cc] = f2bf(v);
                    }
                } else if (EPI == 1) {
                    v = (v + biasu[col]) * qsc;
                    dstu[((size_t)(col >> 6) * N_NODES + row) * HD + (col & 63)] = f2bf(v);
                } else {
                    v += biasu[col];
                    f32a[(size_t)row * E + col] = v;
                }
            }
        }
    }
}

// ---------------------------------------------------------------------------
// flash MHA, S^T formulation, key-split KSPLIT, fixed-max exp2 softmax.
// q is PRE-SCALED by LSC so p = exp2(S) directly (raw v_exp_f32 builtin).
// qh,kh: [H][N][HD] bf16 ; vt: [H][HD][N] bf16
// Opart: [KSPLIT][H][N][HD] fp32 (unnormalized) ; Lpart: [KSPLIT][H][N]
__global__ __launch_bounds__(256)
void flash_mha_k(const short* __restrict__ qh, const short* __restrict__ kh,
                 const short* __restrict__ vt, float* __restrict__ Opart,
                 float* __restrict__ Lpart)
{
    const int h = blockIdx.y, z = blockIdx.z;
    const int q0 = blockIdx.x * 64;
    const int t = threadIdx.x, wave = t >> 6, lane = t & 63;
    const int quad = lane >> 4, l16 = lane & 15;
    const int sw = l16 & 7;

    __shared__ __align__(16) short Kt[64 * 64];
    __shared__ __align__(16) short Vs[64 * 64];
    __shared__ __align__(16) short Pt[4][16 * 64];

    const short* qb = qh + ((size_t)h * N_NODES + q0 + wave * 16 + l16) * HD;
    const bf16x8 aq0 = *(const bf16x8*)(qb + quad * 8);
    const bf16x8 aq1 = *(const bf16x8*)(qb + 32 + quad * 8);

    f32x4 O[4];
    #pragma unroll
    for (int c = 0; c < 4; ++c) O[c] = (f32x4){0.f, 0.f, 0.f, 0.f};
    float lr = 0.f;

    const short* kb = kh + (size_t)h * N_NODES * HD;
    const short* vb = vt + (size_t)h * HD * N_NODES;
    const int c0 = (quad ^ sw) << 3;
    const int c1 = c0 ^ 32;

    const int r_ = t >> 3, ch_ = (t & 7);
    const int lo0 = r_ * 64 + ((ch_ ^ (r_ & 7)) << 3);
    const int r1_ = r_ + 32;
    const int lo1 = r1_ * 64 + ((ch_ ^ (r1_ & 7)) << 3);

    const int kbeg = z * (N_NODES / KSPLIT);
    for (int k0 = kbeg; k0 < kbeg + N_NODES / KSPLIT; k0 += 64) {
        __syncthreads();
        *(bf16x8*)&Kt[lo0] = *(const bf16x8*)(kb + (size_t)(k0 + r_) * HD + ch_ * 8);
        *(bf16x8*)&Vs[lo0] = *(const bf16x8*)(vb + (size_t)r_ * N_NODES + k0 + ch_ * 8);
        *(bf16x8*)&Kt[lo1] = *(const bf16x8*)(kb + (size_t)(k0 + r1_) * HD + ch_ * 8);
        *(bf16x8*)&Vs[lo1] = *(const bf16x8*)(vb + (size_t)r1_ * N_NODES + k0 + ch_ * 8);
        __syncthreads();

        // S^T = K Q^T (q pre-scaled by LSC): rows = keys, cols = queries
        f32x4 S[4];
        #pragma unroll
        for (int c = 0; c < 4; ++c) {
            const int rb = (16 * c + l16) * 64;
            const bf16x8 kf0 = *(const bf16x8*)&Kt[rb + c0];
            const bf16x8 kf1 = *(const bf16x8*)&Kt[rb + c1];
            f32x4 a = {0.f, 0.f, 0.f, 0.f};
            a = __builtin_amdgcn_mfma_f32_16x16x32_bf16(kf0, aq0, a, 0, 0, 0);
            a = __builtin_amdgcn_mfma_f32_16x16x32_bf16(kf1, aq1, a, 0, 0, 0);
            S[c] = a;
        }

        // fixed-max softmax: p = 2^S (raw hw exp2; |S| bounded ~20)
        #pragma unroll
        for (int c = 0; c < 4; ++c)
            #pragma unroll
            for (int r = 0; r < 4; ++r) {
                const float p = __builtin_amdgcn_exp2f(S[c][r]);
                S[c][r] = p;
                lr += p;
            }

        // P[query][key] -> LDS (packed b32), read back as A-fragments
        #pragma unroll
        for (int c = 0; c < 4; ++c) {
            const int chunk = 2 * c + (quad >> 1);
            const int off = l16 * 64 + ((chunk ^ sw) << 3) + (quad & 1) * 4;
            *(unsigned*)&Pt[wave][off]     = packbf2(S[c][0], S[c][1]);
            *(unsigned*)&Pt[wave][off + 2] = packbf2(S[c][2], S[c][3]);
        }
        const bf16x8 pf0 = *(const bf16x8*)&Pt[wave][l16 * 64 + c0];
        const bf16x8 pf1 = *(const bf16x8*)&Pt[wave][l16 * 64 + c1];
        #pragma unroll
        for (int c = 0; c < 4; ++c) {
            const int rb = (16 * c + l16) * 64;
            const bf16x8 vf0 = *(const bf16x8*)&Vs[rb + c0];
            const bf16x8 vf1 = *(const bf16x8*)&Vs[rb + c1];
            O[c] = __builtin_amdgcn_mfma_f32_16x16x32_bf16(pf0, vf0, O[c], 0, 0, 0);
            O[c] = __builtin_amdgcn_mfma_f32_16x16x32_bf16(pf1, vf1, O[c], 0, 0, 0);
        }
    }

    // reduce l across the 4 quads holding the same query l16
    lr += __shfl_xor(lr, 16);
    lr += __shfl_xor(lr, 32);

    const size_t zb = ((size_t)z * NH + h) * N_NODES;
    #pragma unroll
    for (int c = 0; c < 4; ++c)
        #pragma unroll
        for (int r = 0; r < 4; ++r)
            Opart[(zb + q0 + wave * 16 + quad * 4 + r) * HD + 16 * c + l16] = O[c][r];
    if (quad == 0)
        Lpart[zb + q0 + wave * 16 + l16] = lr;
}

// combine the KSPLIT halves -> o (bf16 [N][E]); shift-invariant (no max needed)
__global__ __launch_bounds__(256)
void combine_k(const float* __restrict__ Opart, const float* __restrict__ Lp,
               short* __restrict__ obf)
{
    const int idx = blockIdx.x * 256 + threadIdx.x;
    const int e4 = idx * 4;
    const int q = e4 >> 9;
    const int col = e4 & 511;
    const int h = col >> 6, d = col & 63;
    float4 s = {0.f, 0.f, 0.f, 0.f};
    float l = 0.f;
    #pragma unroll
    for (int z = 0; z < KSPLIT; ++z) {
        const size_t b = ((size_t)z * NH + h) * N_NODES + q;
        const float4 o = *(const float4*)&Opart[b * HD + d];
        s.x += o.x; s.y += o.y; s.z += o.z; s.w += o.w;
        l += Lp[b];
    }
    const float inv = 1.0f / l;
    short4 o;
    o.x = f2bf(s.x * inv); o.y = f2bf(s.y * inv);
    o.z = f2bf(s.z * inv); o.w = f2bf(s.w * inv);
    *(short4*)&obf[(size_t)q * E + col] = o;
}

// ---------------------------------------------------------------------------
__global__ __launch_bounds__(256)
void mask_build_k(const int* __restrict__ ei, unsigned* __restrict__ mask)
{
    const int i = blockIdx.x * 256 + threadIdx.x;
    const int r = ei[i];
    const int c = ei[NEDGE + i];
    atomicOr(&mask[(size_t)r * (N_NODES / 32) + (c >> 5)], 1u << (c & 31));
}

__device__ inline float waveMax(float v) {
    #pragma unroll
    for (int o = 32; o; o >>= 1) v = fmaxf(v, __shfl_xor(v, o));
    return v;
}
__device__ inline float waveSum(float v) {
    #pragma unroll
    for (int o = 32; o; o >>= 1) v += __shfl_xor(v, o);
    return v;
}

// One block per row (round-5 validated form): zero the row, enumerate edge
// columns from the bitmask, fp32 dot(Q[row], K[col]) one edge per wave, exact
// softmax over edges, scatter p, per-row entropy via PLAIN STORE to entRow
// (no atomics anywhere in the entropy path).
__global__ __launch_bounds__(256)
void edge_attn_k(const float* __restrict__ Q, const float* __restrict__ Km,
                 const unsigned* __restrict__ mask, float* __restrict__ attn,
                 float* __restrict__ entRow)
{
    const int row = blockIdx.x;
    const int t = threadIdx.x;
    const int wave = t >> 6, lane = t & 63;
    const size_t rowbase = (size_t)row * N_NODES;

    __shared__ float qrow[E];
    __shared__ int cols[MAXE];
    __shared__ float sc[MAXE];
    __shared__ int cnt;
    __shared__ float red[4];

    {
        const float4 zv = {0.f, 0.f, 0.f, 0.f};
        #pragma unroll
        for (int j = 0; j < 4; ++j)
            *(float4*)&attn[rowbase + j * 1024 + t * 4] = zv;
    }
    qrow[t] = Q[(size_t)row * E + t];
    qrow[256 + t] = Q[(size_t)row * E + 256 + t];
    if (t == 0) cnt = 0;
    __syncthreads();

    if (t < 128) {
        unsigned wm = mask[(size_t)row * (N_NODES / 32) + t];
        while (wm) {
            const int b = __ffs(wm) - 1;
            wm &= wm - 1;
            const int idx = atomicAdd(&cnt, 1);
            cols[idx] = t * 32 + b;
        }
    }
    __syncthreads();
    const int nE = cnt;

    if (nE == 0) {   // uniform row (unreachable for this input, but exact)
        const float p = 1.0f / 4096.0f;
        for (int j = t; j < N_NODES; j += 256) attn[rowbase + j] = p;
        if (t == 0) entRow[row] = -4096.f * p * logf(p + 1e-10f);
        return;
    }

    const float scale = 0.044194173824159216f;   // 1/sqrt(512)
    for (int e = wave; e < nE; e += 4) {
        const float* kr = Km + (size_t)cols[e] * E;
        float acc = 0.f;
        #pragma unroll
        for (int i = 0; i < 2; ++i) {
            const float4 kv = *(const float4*)(kr + i * 256 + lane * 4);
            const float4 qv = *(const float4*)(&qrow[i * 256 + lane * 4]);
            acc += kv.x * qv.x + kv.y * qv.y + kv.z * qv.z + kv.w * qv.w;
        }
        acc = waveSum(acc);
        if (lane == 0) sc[e] = acc * scale;
    }
    __syncthreads();

    float lm = -3.4e38f;
    for (int e = t; e < nE; e += 256) lm = fmaxf(lm, sc[e]);
    lm = waveMax(lm);
    if (lane == 0) red[wave] = lm;
    __syncthreads();
    const float m = fmaxf(fmaxf(red[0], red[1]), fmaxf(red[2], red[3]));
    __syncthreads();

    float ls = 0.f;
    for (int e = t; e < nE; e += 256) ls += expf(sc[e] - m);
    ls = waveSum(ls);
    if (lane == 0) red[wave] = ls;
    __syncthreads();
    const float inv = 1.0f / (red[0] + red[1] + red[2] + red[3]);
    __syncthreads();   // red[] reused below

    float ent = 0.f;
    for (int e = t; e < nE; e += 256) {
        const float p = expf(sc[e] - m) * inv;
        attn[rowbase + cols[e]] = p;
        ent -= p * logf(p + 1e-10f);
    }
    ent = waveSum(ent);
    if (lane == 0) red[wave] = ent;
    __syncthreads();
    if (t == 0) entRow[row] = red[0] + red[1] + red[2] + red[3];
}

// deterministic single-block reduction of entRow -> coherence
__global__ __launch_bounds__(256)
void coh_k(const float* __restrict__ entRow, float* __restrict__ out)
{
    __shared__ float red[4];
    const int t = threadIdx.x;
    float s = 0.f;
    for (int i = t; i < N_NODES; i += 256) s += entRow[i];
    s = waveSum(s);
    if ((t & 63) == 0) red[t >> 6] = s;
    __syncthreads();
    if (t == 0)
        out[0] = 1.0f - (red[0] + red[1] + red[2] + red[3]) / logf(4096.0f);
}

__global__ __launch_bounds__(256)
void phase_k(const float* __restrict__ Q, const float* __restrict__ K,
             float* __restrict__ out)
{
    const size_t i = (size_t)blockIdx.x * 256 + threadIdx.x;
    out[i] = atan2f(K[i], Q[i]);
}

// ---------------------------------------------------------------------------
extern "C" void kernel_launch(void* const* d_in, const int* in_sizes, int n_in,
                              void* d_out, int out_size, void* d_ws, size_t ws_size,
                              hipStream_t stream)
{
    const float* x    = (const float*)d_in[0];
    const int*   ei   = (const int*)  d_in[1];
    const int*   ct   = (const int*)  d_in[2];
    const float* Wq   = (const float*)d_in[3];
    const float* bq   = (const float*)d_in[4];
    const float* Wk   = (const float*)d_in[5];
    const float* bk   = (const float*)d_in[6];
    const float* Wv   = (const float*)d_in[7];
    const float* bv   = (const float*)d_in[8];
    const float* bio  = (const float*)d_in[9];
    const float* cemb = (const float*)d_in[10];
    const float* ipw  = (const float*)d_in[11];
    const float* ipb  = (const float*)d_in[12];
    const float* ow   = (const float*)d_in[13];
    const float* ob   = (const float*)d_in[14];

    const size_t NE = (size_t)N_NODES * E;   // 2,097,152

    // ws: survives until edge_attn/phase
    float* Qf = (float*)d_ws;                 // [4096][512] fp32
    float* Kf = Qf + NE;
    unsigned* mask = (unsigned*)(Kf + NE);    // 2 MB
    float* entRow = (float*)(mask + (size_t)N_NODES * (N_NODES / 32));  // [4096]

    // outputs
    float* outAttended = (float*)d_out;                    // [4096,512]
    float* outAttn  = outAttended + NE;                    // [4096,4096]
    float* outPhase = outAttn + (size_t)N_NODES * N_NODES; // [4096,512]
    float* outCoh   = outPhase + NE;                       // scalar

    // scratch carved from the attn output region (dead until edge_attn).
    // Float-slot offsets, sizes verified (bf16 buffers = elements/2 slots):
    float* Opart = outAttn;                                  //        0 ..  8,388,608
    float* Lpart = outAttn + 8388608;                        //  .. 8,519,680
    short* obf   = (short*)(outAttn + 8519680);              //  .. 9,568,256
    short* vt    = (short*)(outAttn + 9568256);              //  .. 10,616,832
    short* qh    = (short*)(outAttn + 10616832);             //  .. 11,665,408
    short* kh    = (short*)(outAttn + 11665408);             //  .. 12,713,984
    short* Qbf   = (short*)(outAttn + 12713984);             //  .. 13,762,560
    short* Kbf   = (short*)(outAttn + 13762560);             //  .. 14,811,136
    short* xhi   = (short*)(outAttn + 14811136);             //  .. 15,335,424
    short* xlo   = (short*)(outAttn + 15335424);             //  .. 15,859,712
    short* Wthi  = (short*)(outAttn + 15859712);             //  .. 16,056,320
    short* Wtlo  = (short*)(outAttn + 16056320);             //  .. 16,252,928
    short* ipwbf = (short*)(outAttn + 16252928);             //  .. 16,515,072
    short* owbf  = (short*)(outAttn + 16515072);             //  .. 16,646,144
    float* beff  = outAttn + 16646144;                       //  .. 16,647,680 ✓

    const dim3 blk(256);

    (void)hipMemsetAsync(mask, 0, (size_t)N_NODES * (N_NODES / 32) * sizeof(unsigned), stream);
    mask_build_k<<<dim3(NEDGE / 256), blk, 0, stream>>>(ei, mask);

    // effective weights (bio^T staged on the fly for z=0) + all conversions
    prep_gemm_k<<<dim3(4, 8, 3), blk, 0, stream>>>(bio, ipw, Wq, Wk, Wv, Wthi, Wtlo);
    conv_all_k<<<dim3(1798), blk, 0, stream>>>(x, ipw, ow, bq, bk, bv, bio, ipb,
                                               xhi, xlo, ipwbf, owbf, beff);

    // main fused GEMM: [Q|K|v] = x @ Weff^T (+ ce, beff); v -> vt bf16 direct
    mf_gemm_k<true, 0><<<dim3(12, 32, 1), blk, 0, stream>>>(
        xhi, xlo, Wthi, Wtlo, DIN, beff, cemb, ct,
        Qf, Kf, Qbf, Kbf, vt);

    // in_proj q/k -> bf16 head-major (q pre-scaled by LSC)
    mf_gemm_k<false, 1><<<dim3(4, 32, 2), blk, 0, stream>>>(
        Qbf, Kbf, ipwbf, nullptr, E, ipb, nullptr, nullptr,
        nullptr, nullptr, qh, kh, nullptr);

    // flash MHA (key-split 4, fixed-max, raw exp2) + combine
    flash_mha_k<<<dim3(N_NODES / 64, NH, KSPLIT), blk, 0, stream>>>(qh, kh, vt, Opart, Lpart);
    combine_k<<<dim3((unsigned)(NE / 4 / 256)), blk, 0, stream>>>(Opart, Lpart, obf);

    // attended = o @ out_w^T + out_b
    mf_gemm_k<false, 2><<<dim3(4, 32, 1), blk, 0, stream>>>(
        obf, nullptr, owbf, nullptr, E, ob, nullptr, nullptr,
        outAttended, nullptr, nullptr, nullptr, nullptr);

    // phase
    phase_k<<<dim3((unsigned)(NE / 256)), blk, 0, stream>>>(Qf, Kf, outPhase);

    // edge-sparse graph attention + per-row entropy (plain stores)
    edge_attn_k<<<dim3(N_NODES), blk, 0, stream>>>(Qf, Kf, mask, outAttn, entRow);

    // deterministic entropy reduction -> coherence
    coh_k<<<dim3(1), blk, 0, stream>>>(entRow, outCoh);
}